// Round 2
// baseline (1753.194 us; speedup 1.0000x reference)
//
#include <hip/hip_runtime.h>

// ---------------- problem constants ----------------
constexpr int kB   = 2;
constexpr int kN   = 4096;   // tokens (64x64)
constexpr int kC   = 320;    // channels
constexpr int kNA  = 3072;   // src (non-dst) tokens
constexpr int kNB  = 1024;   // dst tokens
constexpr int kNM  = 2048;   // merged seq len (1024 unm + 1024 dst)
constexpr int kR   = 2048;   // merged src count
constexpr int kH   = 8;
constexpr int kDH  = 40;
constexpr int kLC  = 77;
constexpr int kDC  = 768;
constexpr int kDFF = 1280;

__device__ __forceinline__ float wave_sum(float v){
  #pragma unroll
  for (int m=32;m>=1;m>>=1) v += __shfl_xor(v, m, 64);
  return v;
}
__device__ __forceinline__ float wave_max(float v){
  #pragma unroll
  for (int m=32;m>=1;m>>=1) v = fmaxf(v, __shfl_xor(v, m, 64));
  return v;
}
// rank of token t=(h,w) within the ascending list of non-dst tokens
__device__ __forceinline__ int d_arank(int h, int w){
  int base = 32*((h+1)>>1) + 64*(h>>1);
  return base + ((h&1) ? w : (w>>1));
}

// ---------------- ws layout (float offsets) ----------------
constexpr size_t rnd64(size_t x){ return (x + 63) & ~(size_t)63; }
constexpr size_t F_mnA = 0;
constexpr size_t F_mnB = F_mnA + rnd64((size_t)kB*kNA*kC);
constexpr size_t F_y   = F_mnB + rnd64((size_t)kB*kNB*kC);   // y1/y2/y3
constexpr size_t F_xm  = F_y   + rnd64((size_t)kB*kN*kC);
constexpr size_t F_qkv = F_xm  + rnd64((size_t)kB*kNM*kC);   // Q1K1V1, later Ao2
constexpr size_t F_ao1 = F_qkv + rnd64((size_t)3*kB*kNM*kC);
constexpr size_t F_xo1 = F_ao1 + rnd64((size_t)kB*kNM*kC);
constexpr size_t F_net1= F_xo1 + rnd64((size_t)kB*kNM*kC);
constexpr size_t F_net2= F_net1+ rnd64((size_t)kB*kN*kC);
constexpr size_t F_k2  = F_net2+ rnd64((size_t)kB*kN*kC);
constexpr size_t F_v2  = F_k2  + rnd64((size_t)kB*kLC*kC);
constexpr size_t F_g   = F_v2  + rnd64((size_t)kB*kLC*kC);
constexpr size_t F_cnt = F_g   + rnd64((size_t)kB*kN*kDFF);
constexpr size_t I_pack= F_cnt + rnd64((size_t)kB*kNB);      // u64[B*NA]
constexpr size_t I_key = I_pack+ rnd64((size_t)kB*kNA*2);
constexpr size_t I_nidx= I_key + rnd64((size_t)kB*kNA);
constexpr size_t I_mrg = I_nidx+ rnd64((size_t)kB*kNA);
constexpr size_t I_slot= I_mrg + rnd64((size_t)kB*kNA);
constexpr size_t I_unml= I_slot+ rnd64((size_t)kB*kNA);
constexpr size_t I_ucnt= I_unml+ rnd64((size_t)kB*kNB);
constexpr size_t I_aidx= I_ucnt+ rnd64(64);
constexpr size_t I_bidx= I_aidx+ rnd64(kNA);

// ---------------- small setup kernels ----------------
__global__ void k_idx(int* __restrict__ a_idx, int* __restrict__ b_idx){
  int t = blockIdx.x*256 + threadIdx.x;
  if (t >= kN) return;
  int h = t>>6, w = t&63;
  if (!((h|w)&1)) b_idx[(h>>1)*32 + (w>>1)] = t;
  else            a_idx[d_arank(h,w)] = t;
}
__global__ void k_init(unsigned long long* __restrict__ pack, int* __restrict__ ucnt){
  int i = blockIdx.x*256 + threadIdx.x;
  if (i < kB*kNA) pack[i] = 0ull;
  if (i < kB) ucnt[i] = 0;
}
// normalize metric rows and scatter into a/b row order
__global__ void k_gather(const float* __restrict__ net, float* __restrict__ mA, float* __restrict__ mB){
  int blk = blockIdx.x; int b = blk >> 12; int t = blk & 4095;
  int lane = threadIdx.x;
  const float* xp = net + ((size_t)b*kN + t)*kC;
  float v[5]; float s2 = 0.f;
  #pragma unroll
  for (int i=0;i<5;i++){ float f = xp[lane + i*64]; v[i]=f; s2 += f*f; }
  s2 = wave_sum(s2);
  float rn = 1.0f / sqrtf(s2);
  int h=t>>6, w=t&63;
  float* dp;
  if (!((h|w)&1)) dp = mB + ((size_t)b*kNB + ((h>>1)*32+(w>>1)))*kC;
  else            dp = mA + ((size_t)b*kNA + d_arank(h,w))*kC;
  #pragma unroll
  for (int i=0;i<5;i++) dp[lane + i*64] = v[i]*rn;
}

// ---------------- fused score GEMM (NT) + row argmax ----------------
__global__ __launch_bounds__(256) void k_scores(const float* __restrict__ mA, const float* __restrict__ mB,
                                                unsigned long long* __restrict__ pack){
  __shared__ __align__(16) float As[16][68];
  __shared__ __align__(16) float Bs[16][68];
  const int b = blockIdx.z;
  const int m0 = blockIdx.x*64, n0 = blockIdx.y*64;
  const int tid = threadIdx.x;
  const int mr = tid>>4, nc = tid&15;
  const int lr = tid>>2, lc4 = (tid&3)*4;
  const float* Ab = mA + (size_t)b*kNA*kC;
  const float* Bb = mB + (size_t)b*kNB*kC;
  float acc[4][4] = {};
  for (int k0=0; k0<kC; k0+=16){
    __syncthreads();
    {
      float4 av = *reinterpret_cast<const float4*>(&Ab[(size_t)(m0+lr)*kC + k0 + lc4]);
      As[lc4+0][lr]=av.x; As[lc4+1][lr]=av.y; As[lc4+2][lr]=av.z; As[lc4+3][lr]=av.w;
      float4 bv = *reinterpret_cast<const float4*>(&Bb[(size_t)(n0+lr)*kC + k0 + lc4]);
      Bs[lc4+0][lr]=bv.x; Bs[lc4+1][lr]=bv.y; Bs[lc4+2][lr]=bv.z; Bs[lc4+3][lr]=bv.w;
    }
    __syncthreads();
    #pragma unroll
    for (int kk=0;kk<16;kk++){
      const float4 a4 = *reinterpret_cast<const float4*>(&As[kk][mr*4]);
      const float4 b4 = *reinterpret_cast<const float4*>(&Bs[kk][nc*4]);
      const float aa[4]={a4.x,a4.y,a4.z,a4.w};
      const float bb[4]={b4.x,b4.y,b4.z,b4.w};
      #pragma unroll
      for (int i=0;i<4;i++)
        #pragma unroll
        for (int j=0;j<4;j++)
          acc[i][j] = fmaf(aa[i], bb[j], acc[i][j]);
    }
  }
  #pragma unroll
  for (int i=0;i<4;i++){
    float bs = acc[i][0]; int bj = n0 + nc*4;       // ascending j + strict '>' = first argmax
    #pragma unroll
    for (int j=1;j<4;j++){
      float v = acc[i][j];
      if (v > bs){ bs=v; bj=n0+nc*4+j; }
    }
    #pragma unroll
    for (int off=1; off<16; off<<=1){
      float os = __shfl_xor(bs, off, 16);
      int   oj = __shfl_xor(bj, off, 16);
      if (os > bs || (os == bs && oj < bj)){ bs=os; bj=oj; }
    }
    if (nc == 0){
      unsigned int u = __float_as_uint(bs);
      unsigned int key = (u & 0x80000000u) ? ~u : (u | 0x80000000u); // order-preserving
      unsigned long long pk = ((unsigned long long)key << 32) |
                              (unsigned long long)(0xFFFFFFFFu - (unsigned int)bj);
      atomicMax(&pack[(size_t)b*kNA + m0 + mr*4 + i], pk);
    }
  }
}
__global__ void k_decode(const unsigned long long* __restrict__ pack, unsigned int* __restrict__ nmkey,
                         int* __restrict__ node_idx){
  int i = blockIdx.x*256 + threadIdx.x;
  if (i >= kB*kNA) return;
  unsigned long long p = pack[i];
  nmkey[i]    = (unsigned int)(p>>32);
  node_idx[i] = (int)(0xFFFFFFFFu - (unsigned int)(p & 0xFFFFFFFFull));
}
// stable descending rank; rank<kR => merged, else assign an unm slot
__global__ __launch_bounds__(256) void k_rank(const unsigned int* __restrict__ nmkey, int* __restrict__ merged,
                                              int* __restrict__ slot_of, int* __restrict__ unm_list,
                                              int* __restrict__ ucnt){
  __shared__ unsigned int keys[kNA];
  int b = blockIdx.y;
  int i = blockIdx.x*256 + threadIdx.x;
  const unsigned int* kb = nmkey + (size_t)b*kNA;
  for (int idx=threadIdx.x; idx<kNA; idx+=256) keys[idx] = kb[idx];
  __syncthreads();
  unsigned int ki = keys[i];
  int rank = 0;
  for (int j=0;j<kNA;j++){
    unsigned int kj = keys[j];
    rank += (kj > ki) || (kj == ki && j < i);
  }
  int mg = rank < kR;
  merged[(size_t)b*kNA + i] = mg;
  if (!mg){
    int s = atomicAdd(&ucnt[b], 1);
    unm_list[(size_t)b*kNB + s] = i;
    slot_of[(size_t)b*kNA + i] = s;
  }
}

// ---------------- layernorm ----------------
__global__ void k_ln(const float* __restrict__ x, const float* __restrict__ g,
                     const float* __restrict__ be, float* __restrict__ y){
  const int row = blockIdx.x;
  const int lane = threadIdx.x;
  const float* xp = x + (size_t)row*kC;
  float v[5]; float s=0.f, s2=0.f;
  #pragma unroll
  for (int i=0;i<5;i++){ float f = xp[lane + i*64]; v[i]=f; s+=f; s2+=f*f; }
  s = wave_sum(s); s2 = wave_sum(s2);
  float mu = s * (1.0f/kC);
  float var = s2 * (1.0f/kC) - mu*mu;
  float rstd = rsqrtf(var + 1e-5f);
  float* yp = y + (size_t)row*kC;
  #pragma unroll
  for (int i=0;i<5;i++){
    int c = lane + i*64;
    yp[c] = (v[i]-mu)*rstd*g[c] + be[c];
  }
}

// ---------------- merge ----------------
__global__ void k_merge_unm(const float* __restrict__ y, const int* __restrict__ a_idx,
                            const int* __restrict__ unm_list, float* __restrict__ xm){
  int blk = blockIdx.x; int b = blk >> 10; int s = blk & 1023;
  int i = unm_list[(size_t)b*kNB + s];
  int t = a_idx[i];
  const float* sp = y + ((size_t)b*kN + t)*kC;
  float* dp = xm + ((size_t)b*kNM + s)*kC;
  int lane = threadIdx.x;
  #pragma unroll
  for (int q=0;q<5;q++) dp[lane+q*64] = sp[lane+q*64];
}
__global__ void k_merge_dst(const float* __restrict__ y, float* __restrict__ xm, float* __restrict__ cnt){
  int blk = blockIdx.x; int b = blk >> 10; int j = blk & 1023;
  int t = 128*(j>>5) + 2*(j&31);
  const float* sp = y + ((size_t)b*kN + t)*kC;
  float* dp = xm + ((size_t)b*kNM + kNB + j)*kC;
  int lane = threadIdx.x;
  #pragma unroll
  for (int q=0;q<5;q++) dp[lane+q*64] = sp[lane+q*64];
  if (lane==0) cnt[(size_t)b*kNB + j] = 1.0f;
}
__global__ void k_merge_src(const float* __restrict__ y, const int* __restrict__ a_idx,
                            const int* __restrict__ merged, const int* __restrict__ node_idx,
                            float* __restrict__ xm, float* __restrict__ cnt){
  int blk = blockIdx.x; int b = blk / kNA; int i = blk % kNA;
  if (!merged[(size_t)b*kNA + i]) return;
  int t = a_idx[i]; int j = node_idx[(size_t)b*kNA + i];
  const float* sp = y + ((size_t)b*kN + t)*kC;
  float* dp = xm + ((size_t)b*kNM + kNB + j)*kC;
  int lane = threadIdx.x;
  #pragma unroll
  for (int q=0;q<5;q++) atomicAdd(&dp[lane+q*64], sp[lane+q*64]);
  if (lane==0) atomicAdd(&cnt[(size_t)b*kNB + j], 1.0f);
}
__global__ void k_merge_scale(float* __restrict__ xm, const float* __restrict__ cnt){
  int blk = blockIdx.x; int b = blk >> 10; int j = blk & 1023;
  float inv = 1.0f / cnt[(size_t)b*kNB + j];
  float* dp = xm + ((size_t)b*kNM + kNB + j)*kC;
  int lane = threadIdx.x;
  #pragma unroll
  for (int q=0;q<5;q++) dp[lane+q*64] *= inv;
}

// ---------------- generic fp32 GEMM: out = A[MxK] @ W[KxN] (+bias)(+resid) ----------------
// MODE 0: fp32 out; 1: +resid fp32 out; 2: +resid fp32 out (same as 1, kept for clarity)
template<int MODE>
__global__ __launch_bounds__(256) void k_gemm(const float* __restrict__ A, const float* __restrict__ Wt,
    const float* __restrict__ bias, const float* __restrict__ resid, float* __restrict__ out,
    int M, int Nn, int Kk){
  __shared__ __align__(16) float As[16][68];
  __shared__ __align__(16) float Ws[16][68];
  const int tid = threadIdx.x;
  const int m0 = blockIdx.x*64, n0 = blockIdx.y*64;
  const int mr = tid>>4, nc = tid&15;
  const int lr = tid>>2, lc4 = (tid&3)*4;
  const int wr = tid>>4, wc = (tid&15)*4;
  float acc[4][4] = {};
  for (int k0=0; k0<Kk; k0+=16){
    __syncthreads();
    {
      int gm = m0 + lr;
      float4 av;
      if (gm < M) av = *reinterpret_cast<const float4*>(&A[(size_t)gm*Kk + k0 + lc4]);
      else av = make_float4(0.f,0.f,0.f,0.f);
      As[lc4+0][lr]=av.x; As[lc4+1][lr]=av.y; As[lc4+2][lr]=av.z; As[lc4+3][lr]=av.w;
      float4 wv4 = *reinterpret_cast<const float4*>(&Wt[(size_t)(k0+wr)*Nn + (n0+wc)]);
      Ws[wr][wc+0]=wv4.x; Ws[wr][wc+1]=wv4.y; Ws[wr][wc+2]=wv4.z; Ws[wr][wc+3]=wv4.w;
    }
    __syncthreads();
    #pragma unroll
    for (int kk=0;kk<16;kk++){
      const float4 a4 = *reinterpret_cast<const float4*>(&As[kk][mr*4]);
      const float4 b4 = *reinterpret_cast<const float4*>(&Ws[kk][nc*4]);
      const float aa[4]={a4.x,a4.y,a4.z,a4.w};
      const float bb[4]={b4.x,b4.y,b4.z,b4.w};
      #pragma unroll
      for (int i=0;i<4;i++)
        #pragma unroll
        for (int j=0;j<4;j++)
          acc[i][j] = fmaf(aa[i], bb[j], acc[i][j]);
    }
  }
  #pragma unroll
  for (int i=0;i<4;i++){
    int gm = m0 + mr*4 + i;
    if (gm >= M) continue;
    #pragma unroll
    for (int j=0;j<4;j++){
      int gn = n0 + nc*4 + j;
      float v = acc[i][j];
      if (bias) v += bias[gn];
      if (MODE >= 1) v += resid[(size_t)gm*Nn + gn];
      out[(size_t)gm*Nn + gn] = v;
    }
  }
}

// ---------------- fused GEGLU GEMM: G = (A@W[:, :DFF]+b1) * gelu(A@W[:, DFF:]+b2) ----------------
__global__ __launch_bounds__(256) void k_glu(const float* __restrict__ A, const float* __restrict__ Wt,
    const float* __restrict__ bias, float* __restrict__ G, int M){
  __shared__ __align__(16) float As[16][68];
  __shared__ __align__(16) float W1s[16][68];
  __shared__ __align__(16) float W2s[16][68];
  const int tid = threadIdx.x;
  const int m0 = blockIdx.x*64, n0 = blockIdx.y*64;
  const int mr = tid>>4, nc = tid&15;
  const int lr = tid>>2, lc4 = (tid&3)*4;
  const int wr = tid>>4, wc = (tid&15)*4;
  float acc1[4][4] = {}, acc2[4][4] = {};
  for (int k0=0; k0<kC; k0+=16){
    __syncthreads();
    {
      int gm = m0 + lr;
      float4 av;
      if (gm < M) av = *reinterpret_cast<const float4*>(&A[(size_t)gm*kC + k0 + lc4]);
      else av = make_float4(0.f,0.f,0.f,0.f);
      As[lc4+0][lr]=av.x; As[lc4+1][lr]=av.y; As[lc4+2][lr]=av.z; As[lc4+3][lr]=av.w;
      const float* wp = Wt + (size_t)(k0+wr)*(2*kDFF) + (n0+wc);
      float4 w1 = *reinterpret_cast<const float4*>(wp);
      W1s[wr][wc+0]=w1.x; W1s[wr][wc+1]=w1.y; W1s[wr][wc+2]=w1.z; W1s[wr][wc+3]=w1.w;
      float4 w2 = *reinterpret_cast<const float4*>(wp + kDFF);
      W2s[wr][wc+0]=w2.x; W2s[wr][wc+1]=w2.y; W2s[wr][wc+2]=w2.z; W2s[wr][wc+3]=w2.w;
    }
    __syncthreads();
    #pragma unroll
    for (int kk=0;kk<16;kk++){
      const float4 a4 = *reinterpret_cast<const float4*>(&As[kk][mr*4]);
      const float4 b14 = *reinterpret_cast<const float4*>(&W1s[kk][nc*4]);
      const float4 b24 = *reinterpret_cast<const float4*>(&W2s[kk][nc*4]);
      const float aa[4]={a4.x,a4.y,a4.z,a4.w};
      const float bb1[4]={b14.x,b14.y,b14.z,b14.w};
      const float bb2[4]={b24.x,b24.y,b24.z,b24.w};
      #pragma unroll
      for (int i=0;i<4;i++)
        #pragma unroll
        for (int j=0;j<4;j++){
          acc1[i][j] = fmaf(aa[i], bb1[j], acc1[i][j]);
          acc2[i][j] = fmaf(aa[i], bb2[j], acc2[i][j]);
        }
    }
  }
  #pragma unroll
  for (int i=0;i<4;i++){
    int gm = m0 + mr*4 + i;
    if (gm >= M) continue;
    #pragma unroll
    for (int j=0;j<4;j++){
      int gn = n0 + nc*4 + j;
      float xg = acc1[i][j] + bias[gn];
      float gg = acc2[i][j] + bias[kDFF+gn];
      float ge = 0.5f*gg*(1.0f + erff(gg*0.70710678118654752f)); // exact gelu
      G[(size_t)gm*kDFF + gn] = xg * ge;
    }
  }
}

// ---------------- attention ----------------
// self-attn on merged seq: 16 waves/block, 1 q-row per wave, K/V tiles (64 keys) in LDS, online softmax
__global__ __launch_bounds__(1024) void k_attn1(const float* __restrict__ Q, const float* __restrict__ Kp,
                                                const float* __restrict__ Vp, float* __restrict__ O){
  __shared__ __align__(16) float Ks[64][41];
  __shared__ __align__(16) float Vs[64][41];
  __shared__ float qs[16][41];
  __shared__ float ps[16][64];
  const int b = blockIdx.z, hh = blockIdx.y;
  const int tid = threadIdx.x, wv = tid>>6, lane = tid&63;
  const int hoff = hh*kDH;
  const int q = blockIdx.x*16 + wv;
  if (lane < kDH) qs[wv][lane] = Q[((size_t)b*kNM + q)*kC + hoff + lane];
  float m = -1e30f, l = 0.f, o = 0.f;
  for (int kt=0; kt<kNM; kt+=64){
    __syncthreads();
    for (int e=tid; e<64*kDH; e+=1024){
      int kk = e/kDH, d = e - kk*kDH;
      size_t off = ((size_t)b*kNM + kt + kk)*kC + hoff + d;
      Ks[kk][d] = Kp[off];
      Vs[kk][d] = Vp[off];
    }
    __syncthreads();
    float s = 0.f;
    #pragma unroll
    for (int d=0; d<kDH; d++) s = fmaf(qs[wv][d], Ks[lane][d], s);
    s *= 0.15811388300841898f;   // 1/sqrt(40)
    float mt = wave_max(s);
    float mnew = fmaxf(m, mt);
    float alpha = __expf(m - mnew);
    float p = __expf(s - mnew);
    ps[wv][lane] = p;
    float psum = wave_sum(p);
    float acc = 0.f;
    if (lane < kDH){
      #pragma unroll
      for (int k2=0;k2<64;k2++) acc = fmaf(ps[wv][k2], Vs[k2][lane], acc);
    }
    l = l*alpha + psum;
    o = o*alpha + acc;
    m = mnew;
  }
  if (lane < kDH) O[((size_t)b*kNM + q)*kC + hoff + lane] = o / l;
}
// cross-attn: 77 keys fully resident in LDS, one-shot softmax
__global__ __launch_bounds__(1024) void k_attn2(const float* __restrict__ Q, const float* __restrict__ K2,
                                                const float* __restrict__ V2, float* __restrict__ O){
  __shared__ float Ks[kLC][41];
  __shared__ float Vs[kLC][41];
  __shared__ float qs[16][41];
  __shared__ float ps[16][80];
  const int b = blockIdx.z, hh = blockIdx.y;
  const int tid = threadIdx.x, wv = tid>>6, lane = tid&63;
  const int hoff = hh*kDH;
  for (int e=tid; e<kLC*kDH; e+=1024){
    int kk = e/kDH, d = e - kk*kDH;
    size_t off = ((size_t)b*kLC + kk)*kC + hoff + d;
    Ks[kk][d] = K2[off];
    Vs[kk][d] = V2[off];
  }
  const int q = blockIdx.x*16 + wv;
  if (lane < kDH) qs[wv][lane] = Q[((size_t)b*kN + q)*kC + hoff + lane];
  __syncthreads();
  const bool has2 = (lane + 64) < kLC;
  const int k2i = has2 ? lane+64 : 0;
  float s0=0.f, s1=0.f;
  #pragma unroll
  for (int d=0; d<kDH; d++){
    float qd = qs[wv][d];
    s0 = fmaf(qd, Ks[lane][d], s0);
    s1 = fmaf(qd, Ks[k2i][d], s1);
  }
  s0 *= 0.15811388300841898f;
  s1 = has2 ? s1*0.15811388300841898f : -1e30f;
  float mx = wave_max(fmaxf(s0, s1));
  float p0 = __expf(s0-mx);
  float p1 = has2 ? __expf(s1-mx) : 0.f;
  ps[wv][lane] = p0;
  if (has2) ps[wv][64+lane] = p1;
  float l = wave_sum(p0+p1);
  if (lane < kDH){
    float acc = 0.f;
    #pragma unroll
    for (int k3=0;k3<kLC;k3++) acc = fmaf(ps[wv][k3], Vs[k3][lane], acc);
    O[((size_t)b*kN + q)*kC + hoff + lane] = acc / l;
  }
}

// ---------------- unmerge + residual ----------------
__global__ void k_unmerge(const float* __restrict__ net, const float* __restrict__ Xo,
                          const int* __restrict__ merged, const int* __restrict__ node_idx,
                          const int* __restrict__ slot_of, float* __restrict__ net1){
  int blk = blockIdx.x; int b = blk >> 12; int t = blk & 4095;
  int h = t>>6, w = t&63;
  int row;
  if (!((h|w)&1)) row = kNB + ((h>>1)*32 + (w>>1));
  else {
    int i = d_arank(h,w);
    row = merged[(size_t)b*kNA+i] ? (kNB + node_idx[(size_t)b*kNA+i]) : slot_of[(size_t)b*kNA+i];
  }
  const float* np_ = net + ((size_t)b*kN + t)*kC;
  const float* xp = Xo + ((size_t)b*kNM + row)*kC;
  float* op = net1 + ((size_t)b*kN + t)*kC;
  int lane = threadIdx.x;
  #pragma unroll
  for (int q=0;q<5;q++){ int c = lane+q*64; op[c] = np_[c] + xp[c]; }
}

// ---------------- launch ----------------
extern "C" void kernel_launch(void* const* d_in, const int* in_sizes, int n_in,
                              void* d_out, int out_size, void* d_ws, size_t ws_size,
                              hipStream_t stream){
  const float* net = (const float*)d_in[0];
  const float* ctx = (const float*)d_in[1];
  const float* ln1g=(const float*)d_in[2], *ln1b=(const float*)d_in[3];
  const float* ln2g=(const float*)d_in[4], *ln2b=(const float*)d_in[5];
  const float* ln3g=(const float*)d_in[6], *ln3b=(const float*)d_in[7];
  const float* w1q=(const float*)d_in[8],  *w1k=(const float*)d_in[9];
  const float* w1v=(const float*)d_in[10], *w1o=(const float*)d_in[11];
  const float* b1o=(const float*)d_in[12];
  const float* w2q=(const float*)d_in[13], *w2k=(const float*)d_in[14];
  const float* w2v=(const float*)d_in[15], *w2o=(const float*)d_in[16];
  const float* b2o=(const float*)d_in[17];
  const float* fw1=(const float*)d_in[18], *fb1=(const float*)d_in[19];
  const float* fw2=(const float*)d_in[20], *fb2=(const float*)d_in[21];

  float* W = (float*)d_ws;
  float* mnA = W+F_mnA; float* mnB = W+F_mnB; float* y = W+F_y; float* xm = W+F_xm;
  float* Q1 = W+F_qkv; float* K1 = Q1 + (size_t)kB*kNM*kC; float* V1 = K1 + (size_t)kB*kNM*kC;
  float* Ao1 = W+F_ao1; float* Xo1 = W+F_xo1; float* net1 = W+F_net1; float* net2 = W+F_net2;
  float* K2 = W+F_k2; float* V2 = W+F_v2; float* G = W+F_g; float* cnt = W+F_cnt;
  unsigned long long* pack = (unsigned long long*)(W + I_pack);
  unsigned int* nmkey = (unsigned int*)(W + I_key);
  int* nidx = (int*)(W + I_nidx); int* mrg = (int*)(W + I_mrg); int* slot = (int*)(W + I_slot);
  int* unml = (int*)(W + I_unml); int* ucnt = (int*)(W + I_ucnt);
  int* aidx = (int*)(W + I_aidx); int* bidx = (int*)(W + I_bidx);
  float* Q2  = W + F_mnA;   // reuse mnA+mnB (exactly B*N*C floats)
  float* Ao2 = W + F_qkv;   // reuse QKV1 slab

  // --- ToMe indices ---
  k_idx   <<<16, 256, 0, stream>>>(aidx, bidx);
  k_init  <<<(kB*kNA+255)/256, 256, 0, stream>>>(pack, ucnt);
  k_gather<<<kB*kN, 64, 0, stream>>>(net, mnA, mnB);
  k_scores<<<dim3(kNA/64, kNB/64, kB), 256, 0, stream>>>(mnA, mnB, pack);
  k_decode<<<(kB*kNA+255)/256, 256, 0, stream>>>(pack, nmkey, nidx);
  k_rank  <<<dim3(kNA/256, kB), 256, 0, stream>>>(nmkey, mrg, slot, unml, ucnt);
  // --- merge(LN1(net)) ---
  k_ln<<<kB*kN, 64, 0, stream>>>(net, ln1g, ln1b, y);
  k_merge_unm  <<<kB*kNB, 64, 0, stream>>>(y, aidx, unml, xm);
  k_merge_dst  <<<kB*kNB, 64, 0, stream>>>(y, xm, cnt);
  k_merge_src  <<<kB*kNA, 64, 0, stream>>>(y, aidx, mrg, nidx, xm, cnt);
  k_merge_scale<<<kB*kNB, 64, 0, stream>>>(xm, cnt);
  // --- attn1 (self, merged seq) ---
  dim3 g1((kB*kNM+63)/64, kC/64);
  k_gemm<0><<<g1, 256, 0, stream>>>(xm, w1q, nullptr, nullptr, Q1, kB*kNM, kC, kC);
  k_gemm<0><<<g1, 256, 0, stream>>>(xm, w1k, nullptr, nullptr, K1, kB*kNM, kC, kC);
  k_gemm<0><<<g1, 256, 0, stream>>>(xm, w1v, nullptr, nullptr, V1, kB*kNM, kC, kC);
  k_attn1<<<dim3(kNM/16, kH, kB), 1024, 0, stream>>>(Q1, K1, V1, Ao1);
  k_gemm<0><<<g1, 256, 0, stream>>>(Ao1, w1o, b1o, nullptr, Xo1, kB*kNM, kC, kC);
  k_unmerge<<<kB*kN, 64, 0, stream>>>(net, Xo1, mrg, nidx, slot, net1);
  // --- attn2 (cross) ---
  k_ln<<<kB*kN, 64, 0, stream>>>(net1, ln2g, ln2b, y);
  dim3 g2((kB*kN+63)/64, kC/64);
  k_gemm<0><<<g2, 256, 0, stream>>>(y, w2q, nullptr, nullptr, Q2, kB*kN, kC, kC);
  dim3 g3((kB*kLC+63)/64, kC/64);
  k_gemm<0><<<g3, 256, 0, stream>>>(ctx, w2k, nullptr, nullptr, K2, kB*kLC, kC, kDC);
  k_gemm<0><<<g3, 256, 0, stream>>>(ctx, w2v, nullptr, nullptr, V2, kB*kLC, kC, kDC);
  k_attn2<<<dim3(kN/16, kH, kB), 1024, 0, stream>>>(Q2, K2, V2, Ao2);
  k_gemm<1><<<g2, 256, 0, stream>>>(Ao2, w2o, b2o, net1, net2, kB*kN, kC, kC);
  // --- GEGLU FF ---
  k_ln<<<kB*kN, 64, 0, stream>>>(net2, ln3g, ln3b, y);
  k_glu<<<dim3((kB*kN+63)/64, kDFF/64), 256, 0, stream>>>(y, fw1, fb1, G, kB*kN);
  k_gemm<2><<<g2, 256, 0, stream>>>(G, fw2, fb2, net2, (float*)d_out, kB*kN, kC, kDFF);
}

// Round 3
// 1150.188 us; speedup vs baseline: 1.5243x; 1.5243x over previous
//
#include <hip/hip_runtime.h>

// ---------------- problem constants ----------------
constexpr int kB   = 2;
constexpr int kN   = 4096;   // tokens (64x64)
constexpr int kC   = 320;    // channels
constexpr int kNA  = 3072;   // src (non-dst) tokens
constexpr int kNB  = 1024;   // dst tokens
constexpr int kNM  = 2048;   // merged seq len (1024 unm + 1024 dst)
constexpr int kR   = 2048;   // merged src count
constexpr int kH   = 8;
constexpr int kDH  = 40;
constexpr int kLC  = 77;
constexpr int kDC  = 768;
constexpr int kDFF = 1280;

__device__ __forceinline__ float wave_sum(float v){
  #pragma unroll
  for (int m=32;m>=1;m>>=1) v += __shfl_xor(v, m, 64);
  return v;
}
__device__ __forceinline__ float wave_max(float v){
  #pragma unroll
  for (int m=32;m>=1;m>>=1) v = fmaxf(v, __shfl_xor(v, m, 64));
  return v;
}
// rank of token t=(h,w) within the ascending list of non-dst tokens
__device__ __forceinline__ int d_arank(int h, int w){
  int base = 32*((h+1)>>1) + 64*(h>>1);
  return base + ((h&1) ? w : (w>>1));
}

// ---------------- ws layout (float offsets) ----------------
constexpr size_t rnd64(size_t x){ return (x + 63) & ~(size_t)63; }
constexpr size_t F_mnA = 0;
constexpr size_t F_mnB = F_mnA + rnd64((size_t)kB*kNA*kC);
constexpr size_t F_y   = F_mnB + rnd64((size_t)kB*kNB*kC);   // y1/y2/y3
constexpr size_t F_xm  = F_y   + rnd64((size_t)kB*kN*kC);
constexpr size_t F_qkv = F_xm  + rnd64((size_t)kB*kNM*kC);   // Q1K1V1, later Ao2
constexpr size_t F_ao1 = F_qkv + rnd64((size_t)3*kB*kNM*kC);
constexpr size_t F_xo1 = F_ao1 + rnd64((size_t)kB*kNM*kC);
constexpr size_t F_net1= F_xo1 + rnd64((size_t)kB*kNM*kC);
constexpr size_t F_net2= F_net1+ rnd64((size_t)kB*kN*kC);
constexpr size_t F_k2  = F_net2+ rnd64((size_t)kB*kN*kC);
constexpr size_t F_v2  = F_k2  + rnd64((size_t)kB*kLC*kC);
constexpr size_t F_g   = F_v2  + rnd64((size_t)kB*kLC*kC);
constexpr size_t F_cnt = F_g   + rnd64((size_t)kB*kN*kDFF);
constexpr size_t I_pack= F_cnt + rnd64((size_t)kB*kNB);      // u64[B*NA]
constexpr size_t I_key = I_pack+ rnd64((size_t)kB*kNA*2);
constexpr size_t I_nidx= I_key + rnd64((size_t)kB*kNA);
constexpr size_t I_mrg = I_nidx+ rnd64((size_t)kB*kNA);
constexpr size_t I_slot= I_mrg + rnd64((size_t)kB*kNA);
constexpr size_t I_unml= I_slot+ rnd64((size_t)kB*kNA);
constexpr size_t I_ucnt= I_unml+ rnd64((size_t)kB*kNB);
constexpr size_t I_aidx= I_ucnt+ rnd64(64);
constexpr size_t I_bidx= I_aidx+ rnd64(kNA);

// ---------------- small setup kernels ----------------
__global__ void k_idx(int* __restrict__ a_idx, int* __restrict__ b_idx){
  int t = blockIdx.x*256 + threadIdx.x;
  if (t >= kN) return;
  int h = t>>6, w = t&63;
  if (!((h|w)&1)) b_idx[(h>>1)*32 + (w>>1)] = t;
  else            a_idx[d_arank(h,w)] = t;
}
__global__ void k_init(unsigned long long* __restrict__ pack, int* __restrict__ ucnt){
  int i = blockIdx.x*256 + threadIdx.x;
  if (i < kB*kNA) pack[i] = 0ull;
  if (i < kB) ucnt[i] = 0;
}
// normalize metric rows and scatter into a/b row order
__global__ void k_gather(const float* __restrict__ net, float* __restrict__ mA, float* __restrict__ mB){
  int blk = blockIdx.x; int b = blk >> 12; int t = blk & 4095;
  int lane = threadIdx.x;
  const float* xp = net + ((size_t)b*kN + t)*kC;
  float v[5]; float s2 = 0.f;
  #pragma unroll
  for (int i=0;i<5;i++){ float f = xp[lane + i*64]; v[i]=f; s2 += f*f; }
  s2 = wave_sum(s2);
  float rn = 1.0f / sqrtf(s2);
  int h=t>>6, w=t&63;
  float* dp;
  if (!((h|w)&1)) dp = mB + ((size_t)b*kNB + ((h>>1)*32+(w>>1)))*kC;
  else            dp = mA + ((size_t)b*kNA + d_arank(h,w))*kC;
  #pragma unroll
  for (int i=0;i<5;i++) dp[lane + i*64] = v[i]*rn;
}

// ---------------- fused score GEMM (NT) + row argmax ----------------
__global__ __launch_bounds__(256) void k_scores(const float* __restrict__ mA, const float* __restrict__ mB,
                                                unsigned long long* __restrict__ pack){
  __shared__ __align__(16) float As[16][68];
  __shared__ __align__(16) float Bs[16][68];
  const int b = blockIdx.z;
  const int m0 = blockIdx.x*64, n0 = blockIdx.y*64;
  const int tid = threadIdx.x;
  const int mr = tid>>4, nc = tid&15;
  const int lr = tid>>2, lc4 = (tid&3)*4;
  const float* Ab = mA + (size_t)b*kNA*kC;
  const float* Bb = mB + (size_t)b*kNB*kC;
  float acc[4][4] = {};
  for (int k0=0; k0<kC; k0+=16){
    __syncthreads();
    {
      float4 av = *reinterpret_cast<const float4*>(&Ab[(size_t)(m0+lr)*kC + k0 + lc4]);
      As[lc4+0][lr]=av.x; As[lc4+1][lr]=av.y; As[lc4+2][lr]=av.z; As[lc4+3][lr]=av.w;
      float4 bv = *reinterpret_cast<const float4*>(&Bb[(size_t)(n0+lr)*kC + k0 + lc4]);
      Bs[lc4+0][lr]=bv.x; Bs[lc4+1][lr]=bv.y; Bs[lc4+2][lr]=bv.z; Bs[lc4+3][lr]=bv.w;
    }
    __syncthreads();
    #pragma unroll
    for (int kk=0;kk<16;kk++){
      const float4 a4 = *reinterpret_cast<const float4*>(&As[kk][mr*4]);
      const float4 b4 = *reinterpret_cast<const float4*>(&Bs[kk][nc*4]);
      const float aa[4]={a4.x,a4.y,a4.z,a4.w};
      const float bb[4]={b4.x,b4.y,b4.z,b4.w};
      #pragma unroll
      for (int i=0;i<4;i++)
        #pragma unroll
        for (int j=0;j<4;j++)
          acc[i][j] = fmaf(aa[i], bb[j], acc[i][j]);
    }
  }
  #pragma unroll
  for (int i=0;i<4;i++){
    float bs = acc[i][0]; int bj = n0 + nc*4;       // ascending j + strict '>' = first argmax
    #pragma unroll
    for (int j=1;j<4;j++){
      float v = acc[i][j];
      if (v > bs){ bs=v; bj=n0+nc*4+j; }
    }
    #pragma unroll
    for (int off=1; off<16; off<<=1){
      float os = __shfl_xor(bs, off, 16);
      int   oj = __shfl_xor(bj, off, 16);
      if (os > bs || (os == bs && oj < bj)){ bs=os; bj=oj; }
    }
    if (nc == 0){
      unsigned int u = __float_as_uint(bs);
      unsigned int key = (u & 0x80000000u) ? ~u : (u | 0x80000000u); // order-preserving
      unsigned long long pk = ((unsigned long long)key << 32) |
                              (unsigned long long)(0xFFFFFFFFu - (unsigned int)bj);
      atomicMax(&pack[(size_t)b*kNA + m0 + mr*4 + i], pk);
    }
  }
}
__global__ void k_decode(const unsigned long long* __restrict__ pack, unsigned int* __restrict__ nmkey,
                         int* __restrict__ node_idx){
  int i = blockIdx.x*256 + threadIdx.x;
  if (i >= kB*kNA) return;
  unsigned long long p = pack[i];
  nmkey[i]    = (unsigned int)(p>>32);
  node_idx[i] = (int)(0xFFFFFFFFu - (unsigned int)(p & 0xFFFFFFFFull));
}
// stable descending rank; rank<kR => merged, else assign an unm slot
__global__ __launch_bounds__(256) void k_rank(const unsigned int* __restrict__ nmkey, int* __restrict__ merged,
                                              int* __restrict__ slot_of, int* __restrict__ unm_list,
                                              int* __restrict__ ucnt){
  __shared__ unsigned int keys[kNA];
  int b = blockIdx.y;
  int i = blockIdx.x*256 + threadIdx.x;
  const unsigned int* kb = nmkey + (size_t)b*kNA;
  for (int idx=threadIdx.x; idx<kNA; idx+=256) keys[idx] = kb[idx];
  __syncthreads();
  unsigned int ki = keys[i];
  int rank = 0;
  for (int j=0;j<kNA;j++){
    unsigned int kj = keys[j];
    rank += (kj > ki) || (kj == ki && j < i);
  }
  int mg = rank < kR;
  merged[(size_t)b*kNA + i] = mg;
  if (!mg){
    int s = atomicAdd(&ucnt[b], 1);
    unm_list[(size_t)b*kNB + s] = i;
    slot_of[(size_t)b*kNA + i] = s;
  }
}

// ---------------- layernorm ----------------
__global__ void k_ln(const float* __restrict__ x, const float* __restrict__ g,
                     const float* __restrict__ be, float* __restrict__ y){
  const int row = blockIdx.x;
  const int lane = threadIdx.x;
  const float* xp = x + (size_t)row*kC;
  float v[5]; float s=0.f, s2=0.f;
  #pragma unroll
  for (int i=0;i<5;i++){ float f = xp[lane + i*64]; v[i]=f; s+=f; s2+=f*f; }
  s = wave_sum(s); s2 = wave_sum(s2);
  float mu = s * (1.0f/kC);
  float var = s2 * (1.0f/kC) - mu*mu;
  float rstd = rsqrtf(var + 1e-5f);
  float* yp = y + (size_t)row*kC;
  #pragma unroll
  for (int i=0;i<5;i++){
    int c = lane + i*64;
    yp[c] = (v[i]-mu)*rstd*g[c] + be[c];
  }
}

// ---------------- merge ----------------
__global__ void k_merge_unm(const float* __restrict__ y, const int* __restrict__ a_idx,
                            const int* __restrict__ unm_list, float* __restrict__ xm){
  int blk = blockIdx.x; int b = blk >> 10; int s = blk & 1023;
  int i = unm_list[(size_t)b*kNB + s];
  int t = a_idx[i];
  const float* sp = y + ((size_t)b*kN + t)*kC;
  float* dp = xm + ((size_t)b*kNM + s)*kC;
  int lane = threadIdx.x;
  #pragma unroll
  for (int q=0;q<5;q++) dp[lane+q*64] = sp[lane+q*64];
}
__global__ void k_merge_dst(const float* __restrict__ y, float* __restrict__ xm, float* __restrict__ cnt){
  int blk = blockIdx.x; int b = blk >> 10; int j = blk & 1023;
  int t = 128*(j>>5) + 2*(j&31);
  const float* sp = y + ((size_t)b*kN + t)*kC;
  float* dp = xm + ((size_t)b*kNM + kNB + j)*kC;
  int lane = threadIdx.x;
  #pragma unroll
  for (int q=0;q<5;q++) dp[lane+q*64] = sp[lane+q*64];
  if (lane==0) cnt[(size_t)b*kNB + j] = 1.0f;
}
__global__ void k_merge_src(const float* __restrict__ y, const int* __restrict__ a_idx,
                            const int* __restrict__ merged, const int* __restrict__ node_idx,
                            float* __restrict__ xm, float* __restrict__ cnt){
  int blk = blockIdx.x; int b = blk / kNA; int i = blk % kNA;
  if (!merged[(size_t)b*kNA + i]) return;
  int t = a_idx[i]; int j = node_idx[(size_t)b*kNA + i];
  const float* sp = y + ((size_t)b*kN + t)*kC;
  float* dp = xm + ((size_t)b*kNM + kNB + j)*kC;
  int lane = threadIdx.x;
  #pragma unroll
  for (int q=0;q<5;q++) atomicAdd(&dp[lane+q*64], sp[lane+q*64]);
  if (lane==0) atomicAdd(&cnt[(size_t)b*kNB + j], 1.0f);
}
__global__ void k_merge_scale(float* __restrict__ xm, const float* __restrict__ cnt){
  int blk = blockIdx.x; int b = blk >> 10; int j = blk & 1023;
  float inv = 1.0f / cnt[(size_t)b*kNB + j];
  float* dp = xm + ((size_t)b*kNM + kNB + j)*kC;
  int lane = threadIdx.x;
  #pragma unroll
  for (int q=0;q<5;q++) dp[lane+q*64] *= inv;
}

// ---------------- generic fp32 GEMM: out = A[MxK] @ W[KxN] (+bias)(+resid) ----------------
template<int MODE>
__global__ __launch_bounds__(256) void k_gemm(const float* __restrict__ A, const float* __restrict__ Wt,
    const float* __restrict__ bias, const float* __restrict__ resid, float* __restrict__ out,
    int M, int Nn, int Kk){
  __shared__ __align__(16) float As[16][68];
  __shared__ __align__(16) float Ws[16][68];
  const int tid = threadIdx.x;
  const int m0 = blockIdx.x*64, n0 = blockIdx.y*64;
  const int mr = tid>>4, nc = tid&15;
  const int lr = tid>>2, lc4 = (tid&3)*4;
  const int wr = tid>>4, wc = (tid&15)*4;
  float acc[4][4] = {};
  for (int k0=0; k0<Kk; k0+=16){
    __syncthreads();
    {
      int gm = m0 + lr;
      float4 av;
      if (gm < M) av = *reinterpret_cast<const float4*>(&A[(size_t)gm*Kk + k0 + lc4]);
      else av = make_float4(0.f,0.f,0.f,0.f);
      As[lc4+0][lr]=av.x; As[lc4+1][lr]=av.y; As[lc4+2][lr]=av.z; As[lc4+3][lr]=av.w;
      float4 wv4 = *reinterpret_cast<const float4*>(&Wt[(size_t)(k0+wr)*Nn + (n0+wc)]);
      Ws[wr][wc+0]=wv4.x; Ws[wr][wc+1]=wv4.y; Ws[wr][wc+2]=wv4.z; Ws[wr][wc+3]=wv4.w;
    }
    __syncthreads();
    #pragma unroll
    for (int kk=0;kk<16;kk++){
      const float4 a4 = *reinterpret_cast<const float4*>(&As[kk][mr*4]);
      const float4 b4 = *reinterpret_cast<const float4*>(&Ws[kk][nc*4]);
      const float aa[4]={a4.x,a4.y,a4.z,a4.w};
      const float bb[4]={b4.x,b4.y,b4.z,b4.w};
      #pragma unroll
      for (int i=0;i<4;i++)
        #pragma unroll
        for (int j=0;j<4;j++)
          acc[i][j] = fmaf(aa[i], bb[j], acc[i][j]);
    }
  }
  #pragma unroll
  for (int i=0;i<4;i++){
    int gm = m0 + mr*4 + i;
    if (gm >= M) continue;
    #pragma unroll
    for (int j=0;j<4;j++){
      int gn = n0 + nc*4 + j;
      float v = acc[i][j];
      if (bias) v += bias[gn];
      if (MODE >= 1) v += resid[(size_t)gm*Nn + gn];
      out[(size_t)gm*Nn + gn] = v;
    }
  }
}

// ---------------- fused GEGLU GEMM: G = (A@W[:, :DFF]+b1) * gelu(A@W[:, DFF:]+b2) ----------------
__global__ __launch_bounds__(256) void k_glu(const float* __restrict__ A, const float* __restrict__ Wt,
    const float* __restrict__ bias, float* __restrict__ G, int M){
  __shared__ __align__(16) float As[16][68];
  __shared__ __align__(16) float W1s[16][68];
  __shared__ __align__(16) float W2s[16][68];
  const int tid = threadIdx.x;
  const int m0 = blockIdx.x*64, n0 = blockIdx.y*64;
  const int mr = tid>>4, nc = tid&15;
  const int lr = tid>>2, lc4 = (tid&3)*4;
  const int wr = tid>>4, wc = (tid&15)*4;
  float acc1[4][4] = {}, acc2[4][4] = {};
  for (int k0=0; k0<kC; k0+=16){
    __syncthreads();
    {
      int gm = m0 + lr;
      float4 av;
      if (gm < M) av = *reinterpret_cast<const float4*>(&A[(size_t)gm*kC + k0 + lc4]);
      else av = make_float4(0.f,0.f,0.f,0.f);
      As[lc4+0][lr]=av.x; As[lc4+1][lr]=av.y; As[lc4+2][lr]=av.z; As[lc4+3][lr]=av.w;
      const float* wp = Wt + (size_t)(k0+wr)*(2*kDFF) + (n0+wc);
      float4 w1 = *reinterpret_cast<const float4*>(wp);
      W1s[wr][wc+0]=w1.x; W1s[wr][wc+1]=w1.y; W1s[wr][wc+2]=w1.z; W1s[wr][wc+3]=w1.w;
      float4 w2 = *reinterpret_cast<const float4*>(wp + kDFF);
      W2s[wr][wc+0]=w2.x; W2s[wr][wc+1]=w2.y; W2s[wr][wc+2]=w2.z; W2s[wr][wc+3]=w2.w;
    }
    __syncthreads();
    #pragma unroll
    for (int kk=0;kk<16;kk++){
      const float4 a4 = *reinterpret_cast<const float4*>(&As[kk][mr*4]);
      const float4 b14 = *reinterpret_cast<const float4*>(&W1s[kk][nc*4]);
      const float4 b24 = *reinterpret_cast<const float4*>(&W2s[kk][nc*4]);
      const float aa[4]={a4.x,a4.y,a4.z,a4.w};
      const float bb1[4]={b14.x,b14.y,b14.z,b14.w};
      const float bb2[4]={b24.x,b24.y,b24.z,b24.w};
      #pragma unroll
      for (int i=0;i<4;i++)
        #pragma unroll
        for (int j=0;j<4;j++){
          acc1[i][j] = fmaf(aa[i], bb1[j], acc1[i][j]);
          acc2[i][j] = fmaf(aa[i], bb2[j], acc2[i][j]);
        }
    }
  }
  #pragma unroll
  for (int i=0;i<4;i++){
    int gm = m0 + mr*4 + i;
    if (gm >= M) continue;
    #pragma unroll
    for (int j=0;j<4;j++){
      int gn = n0 + nc*4 + j;
      float xg = acc1[i][j] + bias[gn];
      float gg = acc2[i][j] + bias[kDFF+gn];
      float ge = 0.5f*gg*(1.0f + erff(gg*0.70710678118654752f)); // exact gelu
      G[(size_t)gm*kDFF + gn] = xg * ge;
    }
  }
}

// ---------------- attention ----------------
// flash self-attn on merged seq: 256 thr/block, 64-query tile, 64-key tiles.
// S = Q.K^T via 4x4 register microtiles from transposed LDS ([d][token], stride 68).
// Row softmax via shfl_xor within 16-lane row groups; P -> LDS; O += P.V via
// 1row x 10col per thread reading Vt[c][kk] float4s (broadcast-friendly).
__global__ __launch_bounds__(256) void k_attn1(const float* __restrict__ Q, const float* __restrict__ Kp,
                                               const float* __restrict__ Vp, float* __restrict__ O){
  __shared__ __align__(16) float Qt[kDH][68];
  __shared__ __align__(16) float Kt[kDH][68];
  __shared__ __align__(16) float Vt[kDH][68];
  __shared__ __align__(16) float Ps[64][68];
  __shared__ float alpha_s[64];
  __shared__ float ls[64];
  const int b = blockIdx.z, hh = blockIdx.y;
  const int q0 = blockIdx.x*64;
  const int tid = threadIdx.x;
  const int mr = tid>>4, nc = tid&15;      // S-phase mapping: rows mr*4.., cols nc*4..
  const int r2 = tid>>2, cg = tid&3, c0 = cg*10;  // PV mapping: row r2, cols c0..c0+9
  const float scale = 0.15811388300841898f; // 1/sqrt(40)
  const float* Qb = Q  + ((size_t)b*kNM + q0)*kC + hh*kDH;
  const float* Kb = Kp + ((size_t)b*kNM)*kC + hh*kDH;
  const float* Vb = Vp + ((size_t)b*kNM)*kC + hh*kDH;
  // stage Q transposed (once)
  for (int e = tid; e < 640; e += 256){
    int row = e/10, c4 = (e - row*10)*4;
    float4 v = *reinterpret_cast<const float4*>(Qb + (size_t)row*kC + c4);
    Qt[c4+0][row]=v.x; Qt[c4+1][row]=v.y; Qt[c4+2][row]=v.z; Qt[c4+3][row]=v.w;
  }
  float m_i[4], l_i[4], oacc[10];
  #pragma unroll
  for (int i=0;i<4;i++){ m_i[i] = -1e30f; l_i[i] = 0.f; }
  #pragma unroll
  for (int j=0;j<10;j++) oacc[j] = 0.f;
  for (int kt = 0; kt < kNM; kt += 64){
    __syncthreads();   // prev PV done before Kt/Vt/Ps overwrite; Qt staged
    for (int e = tid; e < 640; e += 256){
      int row = e/10, c4 = (e - row*10)*4;
      float4 v = *reinterpret_cast<const float4*>(Kb + (size_t)(kt+row)*kC + c4);
      Kt[c4+0][row]=v.x; Kt[c4+1][row]=v.y; Kt[c4+2][row]=v.z; Kt[c4+3][row]=v.w;
      float4 u = *reinterpret_cast<const float4*>(Vb + (size_t)(kt+row)*kC + c4);
      Vt[c4+0][row]=u.x; Vt[c4+1][row]=u.y; Vt[c4+2][row]=u.z; Vt[c4+3][row]=u.w;
    }
    __syncthreads();
    float acc[4][4] = {};
    #pragma unroll 8
    for (int k=0;k<kDH;k++){
      const float4 q4 = *reinterpret_cast<const float4*>(&Qt[k][mr*4]);
      const float4 k4 = *reinterpret_cast<const float4*>(&Kt[k][nc*4]);
      const float qa[4]={q4.x,q4.y,q4.z,q4.w};
      const float ka[4]={k4.x,k4.y,k4.z,k4.w};
      #pragma unroll
      for (int i=0;i<4;i++)
        #pragma unroll
        for (int j=0;j<4;j++)
          acc[i][j] = fmaf(qa[i], ka[j], acc[i][j]);
    }
    #pragma unroll
    for (int i=0;i<4;i++){
      float s0=acc[i][0]*scale, s1=acc[i][1]*scale, s2=acc[i][2]*scale, s3=acc[i][3]*scale;
      float rm = fmaxf(fmaxf(s0,s1), fmaxf(s2,s3));
      #pragma unroll
      for (int off=1; off<16; off<<=1) rm = fmaxf(rm, __shfl_xor(rm, off, 64));
      float mnew = fmaxf(m_i[i], rm);
      float alpha = __expf(m_i[i] - mnew);
      float p0=__expf(s0-mnew), p1=__expf(s1-mnew), p2=__expf(s2-mnew), p3=__expf(s3-mnew);
      float psum = p0+p1+p2+p3;
      #pragma unroll
      for (int off=1; off<16; off<<=1) psum += __shfl_xor(psum, off, 64);
      l_i[i] = l_i[i]*alpha + psum;
      m_i[i] = mnew;
      int r = mr*4 + i;
      *reinterpret_cast<float4*>(&Ps[r][nc*4]) = make_float4(p0,p1,p2,p3);
      if (nc==0) alpha_s[r] = alpha;
    }
    __syncthreads();
    float av = alpha_s[r2];
    #pragma unroll
    for (int j=0;j<10;j++) oacc[j] *= av;
    for (int kk=0; kk<64; kk+=4){
      const float4 p = *reinterpret_cast<const float4*>(&Ps[r2][kk]);
      #pragma unroll
      for (int j=0;j<10;j++){
        const float4 v = *reinterpret_cast<const float4*>(&Vt[c0+j][kk]);
        oacc[j] += p.x*v.x + p.y*v.y + p.z*v.z + p.w*v.w;
      }
    }
  }
  if (nc==0){
    #pragma unroll
    for (int i=0;i<4;i++) ls[mr*4+i] = l_i[i];
  }
  __syncthreads();
  float inv = 1.0f / ls[r2];
  float* Ob = O + ((size_t)b*kNM + q0 + r2)*kC + hh*kDH + c0;
  #pragma unroll
  for (int j=0;j<10;j++) Ob[j] = oacc[j]*inv;
}

// cross-attn: 77 keys fully resident in LDS, one-shot softmax
__global__ __launch_bounds__(1024) void k_attn2(const float* __restrict__ Q, const float* __restrict__ K2,
                                                const float* __restrict__ V2, float* __restrict__ O){
  __shared__ float Ks[kLC][41];
  __shared__ float Vs[kLC][41];
  __shared__ float qs[16][41];
  __shared__ float ps[16][80];
  const int b = blockIdx.z, hh = blockIdx.y;
  const int tid = threadIdx.x, wv = tid>>6, lane = tid&63;
  const int hoff = hh*kDH;
  for (int e=tid; e<kLC*kDH; e+=1024){
    int kk = e/kDH, d = e - kk*kDH;
    size_t off = ((size_t)b*kLC + kk)*kC + hoff + d;
    Ks[kk][d] = K2[off];
    Vs[kk][d] = V2[off];
  }
  const int q = blockIdx.x*16 + wv;
  if (lane < kDH) qs[wv][lane] = Q[((size_t)b*kN + q)*kC + hoff + lane];
  __syncthreads();
  const bool has2 = (lane + 64) < kLC;
  const int k2i = has2 ? lane+64 : 0;
  float s0=0.f, s1=0.f;
  #pragma unroll
  for (int d=0; d<kDH; d++){
    float qd = qs[wv][d];
    s0 = fmaf(qd, Ks[lane][d], s0);
    s1 = fmaf(qd, Ks[k2i][d], s1);
  }
  s0 *= 0.15811388300841898f;
  s1 = has2 ? s1*0.15811388300841898f : -1e30f;
  float mx = wave_max(fmaxf(s0, s1));
  float p0 = __expf(s0-mx);
  float p1 = has2 ? __expf(s1-mx) : 0.f;
  ps[wv][lane] = p0;
  if (has2) ps[wv][64+lane] = p1;
  float l = wave_sum(p0+p1);
  if (lane < kDH){
    float acc = 0.f;
    #pragma unroll
    for (int k3=0;k3<kLC;k3++) acc = fmaf(ps[wv][k3], Vs[k3][lane], acc);
    O[((size_t)b*kN + q)*kC + hoff + lane] = acc / l;
  }
}

// ---------------- unmerge + residual ----------------
__global__ void k_unmerge(const float* __restrict__ net, const float* __restrict__ Xo,
                          const int* __restrict__ merged, const int* __restrict__ node_idx,
                          const int* __restrict__ slot_of, float* __restrict__ net1){
  int blk = blockIdx.x; int b = blk >> 12; int t = blk & 4095;
  int h = t>>6, w = t&63;
  int row;
  if (!((h|w)&1)) row = kNB + ((h>>1)*32 + (w>>1));
  else {
    int i = d_arank(h,w);
    row = merged[(size_t)b*kNA+i] ? (kNB + node_idx[(size_t)b*kNA+i]) : slot_of[(size_t)b*kNA+i];
  }
  const float* np_ = net + ((size_t)b*kN + t)*kC;
  const float* xp = Xo + ((size_t)b*kNM + row)*kC;
  float* op = net1 + ((size_t)b*kN + t)*kC;
  int lane = threadIdx.x;
  #pragma unroll
  for (int q=0;q<5;q++){ int c = lane+q*64; op[c] = np_[c] + xp[c]; }
}

// ---------------- launch ----------------
extern "C" void kernel_launch(void* const* d_in, const int* in_sizes, int n_in,
                              void* d_out, int out_size, void* d_ws, size_t ws_size,
                              hipStream_t stream){
  const float* net = (const float*)d_in[0];
  const float* ctx = (const float*)d_in[1];
  const float* ln1g=(const float*)d_in[2], *ln1b=(const float*)d_in[3];
  const float* ln2g=(const float*)d_in[4], *ln2b=(const float*)d_in[5];
  const float* ln3g=(const float*)d_in[6], *ln3b=(const float*)d_in[7];
  const float* w1q=(const float*)d_in[8],  *w1k=(const float*)d_in[9];
  const float* w1v=(const float*)d_in[10], *w1o=(const float*)d_in[11];
  const float* b1o=(const float*)d_in[12];
  const float* w2q=(const float*)d_in[13], *w2k=(const float*)d_in[14];
  const float* w2v=(const float*)d_in[15], *w2o=(const float*)d_in[16];
  const float* b2o=(const float*)d_in[17];
  const float* fw1=(const float*)d_in[18], *fb1=(const float*)d_in[19];
  const float* fw2=(const float*)d_in[20], *fb2=(const float*)d_in[21];

  float* W = (float*)d_ws;
  float* mnA = W+F_mnA; float* mnB = W+F_mnB; float* y = W+F_y; float* xm = W+F_xm;
  float* Q1 = W+F_qkv; float* K1 = Q1 + (size_t)kB*kNM*kC; float* V1 = K1 + (size_t)kB*kNM*kC;
  float* Ao1 = W+F_ao1; float* Xo1 = W+F_xo1; float* net1 = W+F_net1; float* net2 = W+F_net2;
  float* K2 = W+F_k2; float* V2 = W+F_v2; float* G = W+F_g; float* cnt = W+F_cnt;
  unsigned long long* pack = (unsigned long long*)(W + I_pack);
  unsigned int* nmkey = (unsigned int*)(W + I_key);
  int* nidx = (int*)(W + I_nidx); int* mrg = (int*)(W + I_mrg); int* slot = (int*)(W + I_slot);
  int* unml = (int*)(W + I_unml); int* ucnt = (int*)(W + I_ucnt);
  int* aidx = (int*)(W + I_aidx); int* bidx = (int*)(W + I_bidx);
  float* Q2  = W + F_mnA;   // reuse mnA+mnB (exactly B*N*C floats)
  float* Ao2 = W + F_qkv;   // reuse QKV1 slab

  // --- ToMe indices ---
  k_idx   <<<16, 256, 0, stream>>>(aidx, bidx);
  k_init  <<<(kB*kNA+255)/256, 256, 0, stream>>>(pack, ucnt);
  k_gather<<<kB*kN, 64, 0, stream>>>(net, mnA, mnB);
  k_scores<<<dim3(kNA/64, kNB/64, kB), 256, 0, stream>>>(mnA, mnB, pack);
  k_decode<<<(kB*kNA+255)/256, 256, 0, stream>>>(pack, nmkey, nidx);
  k_rank  <<<dim3(kNA/256, kB), 256, 0, stream>>>(nmkey, mrg, slot, unml, ucnt);
  // --- merge(LN1(net)) ---
  k_ln<<<kB*kN, 64, 0, stream>>>(net, ln1g, ln1b, y);
  k_merge_unm  <<<kB*kNB, 64, 0, stream>>>(y, aidx, unml, xm);
  k_merge_dst  <<<kB*kNB, 64, 0, stream>>>(y, xm, cnt);
  k_merge_src  <<<kB*kNA, 64, 0, stream>>>(y, aidx, mrg, nidx, xm, cnt);
  k_merge_scale<<<kB*kNB, 64, 0, stream>>>(xm, cnt);
  // --- attn1 (self, merged seq) ---
  dim3 g1((kB*kNM+63)/64, kC/64);
  k_gemm<0><<<g1, 256, 0, stream>>>(xm, w1q, nullptr, nullptr, Q1, kB*kNM, kC, kC);
  k_gemm<0><<<g1, 256, 0, stream>>>(xm, w1k, nullptr, nullptr, K1, kB*kNM, kC, kC);
  k_gemm<0><<<g1, 256, 0, stream>>>(xm, w1v, nullptr, nullptr, V1, kB*kNM, kC, kC);
  k_attn1<<<dim3(kNM/64, kH, kB), 256, 0, stream>>>(Q1, K1, V1, Ao1);
  k_gemm<0><<<g1, 256, 0, stream>>>(Ao1, w1o, b1o, nullptr, Xo1, kB*kNM, kC, kC);
  k_unmerge<<<kB*kN, 64, 0, stream>>>(net, Xo1, mrg, nidx, slot, net1);
  // --- attn2 (cross) ---
  k_ln<<<kB*kN, 64, 0, stream>>>(net1, ln2g, ln2b, y);
  dim3 g2((kB*kN+63)/64, kC/64);
  k_gemm<0><<<g2, 256, 0, stream>>>(y, w2q, nullptr, nullptr, Q2, kB*kN, kC, kC);
  dim3 g3((kB*kLC+63)/64, kC/64);
  k_gemm<0><<<g3, 256, 0, stream>>>(ctx, w2k, nullptr, nullptr, K2, kB*kLC, kC, kDC);
  k_gemm<0><<<g3, 256, 0, stream>>>(ctx, w2v, nullptr, nullptr, V2, kB*kLC, kC, kDC);
  k_attn2<<<dim3(kN/16, kH, kB), 1024, 0, stream>>>(Q2, K2, V2, Ao2);
  k_gemm<1><<<g2, 256, 0, stream>>>(Ao2, w2o, b2o, net1, net2, kB*kN, kC, kC);
  // --- GEGLU FF ---
  k_ln<<<kB*kN, 64, 0, stream>>>(net2, ln3g, ln3b, y);
  k_glu<<<dim3((kB*kN+63)/64, kDFF/64), 256, 0, stream>>>(y, fw1, fb1, G, kB*kN);
  k_gemm<2><<<g2, 256, 0, stream>>>(G, fw2, fb2, net2, (float*)d_out, kB*kN, kC, kDFF);
}

// Round 4
// 955.008 us; speedup vs baseline: 1.8358x; 1.2044x over previous
//
#include <hip/hip_runtime.h>

typedef __attribute__((ext_vector_type(8))) short bf16x8;
typedef __attribute__((ext_vector_type(4))) float f32x4;

// ---------------- problem constants ----------------
constexpr int kB   = 2;
constexpr int kN   = 4096;   // tokens (64x64)
constexpr int kC   = 320;    // channels
constexpr int kNA  = 3072;   // src (non-dst) tokens
constexpr int kNB  = 1024;   // dst tokens
constexpr int kNM  = 2048;   // merged seq len
constexpr int kR   = 2048;   // merged src count
constexpr int kH   = 8;
constexpr int kDH  = 40;
constexpr int kLC  = 77;
constexpr int kDC  = 768;
constexpr int kDFF = 1280;

__device__ __forceinline__ unsigned short f2b(float f){
  unsigned u = __float_as_uint(f);
  u += 0x7FFF + ((u>>16)&1);
  return (unsigned short)(u>>16);
}
__device__ __forceinline__ float b2f(unsigned short h){ return __uint_as_float(((unsigned)h)<<16); }

__device__ __forceinline__ float wave_sum(float v){
  #pragma unroll
  for (int m=32;m>=1;m>>=1) v += __shfl_xor(v, m, 64);
  return v;
}
__device__ __forceinline__ float wave_max(float v){
  #pragma unroll
  for (int m=32;m>=1;m>>=1) v = fmaxf(v, __shfl_xor(v, m, 64));
  return v;
}
__device__ __forceinline__ int d_arank(int h, int w){
  int base = 32*((h+1)>>1) + 64*(h>>1);
  return base + ((h&1) ? w : (w>>1));
}

// ---------------- ws layout (byte offsets) ----------------
constexpr size_t rndB(size_t x){ return (x + 255) & ~(size_t)255; }
constexpr size_t B_mnA  = 0;                                             // fp32 [2*3072*320]
constexpr size_t B_mnB  = rndB(B_mnA + (size_t)kB*kNA*kC*4);             // fp32 [2*1024*320]
constexpr size_t B_y32  = rndB(B_mnB + (size_t)kB*kNB*kC*4);             // fp32 [2*4096*320] (LN1)
constexpr size_t B_xm   = rndB(B_y32 + (size_t)kB*kN*kC*4);              // fp32 [2*2048*320]
constexpr size_t B_xo1  = rndB(B_xm  + (size_t)kB*kNM*kC*4);             // fp32 [2*2048*320]
constexpr size_t B_net1 = rndB(B_xo1 + (size_t)kB*kNM*kC*4);             // fp32 [2*4096*320]
constexpr size_t B_H    = 0;  // bf16 [8192*2560] overlays mnA..net1 (41.94 MB, all dead by then)
constexpr size_t B_net2 = rndB(B_net1 + (size_t)kB*kN*kC*4);             // fp32 [2*4096*320]
constexpr size_t B_G    = rndB(B_net2 + (size_t)kB*kN*kC*4);             // bf16 [8192*1280]
constexpr size_t B_QKVb = rndB(B_G    + (size_t)kB*kN*kDFF*2);           // bf16 [4096*960]
constexpr size_t B_yb   = rndB(B_QKVb + (size_t)kB*kNM*960*2);           // bf16 [8192*320]
constexpr size_t B_xmb  = rndB(B_yb   + (size_t)kB*kN*kC*2);             // bf16 [4096*320]
constexpr size_t B_Ao1b = rndB(B_xmb  + (size_t)kB*kNM*kC*2);            // bf16 [4096*320]
constexpr size_t B_Q2b  = rndB(B_Ao1b + (size_t)kB*kNM*kC*2);            // bf16 [8192*320]
constexpr size_t B_Ao2b = rndB(B_Q2b  + (size_t)kB*kN*kC*2);             // bf16 [8192*320]
constexpr size_t B_KV2b = rndB(B_Ao2b + (size_t)kB*kN*kC*2);             // bf16 [154*640]
constexpr size_t B_ctxb = rndB(B_KV2b + (size_t)kB*kLC*640*2);           // bf16 [154*768]
constexpr size_t B_Wqkv = rndB(B_ctxb + (size_t)kB*kLC*kDC*2);           // bf16 [960*320]
constexpr size_t B_Wo1  = rndB(B_Wqkv + (size_t)960*320*2);              // bf16 [320*320]
constexpr size_t B_Wq2  = rndB(B_Wo1  + (size_t)320*320*2);
constexpr size_t B_Wkv2 = rndB(B_Wq2  + (size_t)320*320*2);              // bf16 [640*768]
constexpr size_t B_Wo2  = rndB(B_Wkv2 + (size_t)640*768*2);
constexpr size_t B_Wff1 = rndB(B_Wo2  + (size_t)320*320*2);              // bf16 [2560*320]
constexpr size_t B_Wff2 = rndB(B_Wff1 + (size_t)2560*320*2);             // bf16 [320*1280]
constexpr size_t B_cnt  = rndB(B_Wff2 + (size_t)320*1280*2);             // fp32 [2*1024]
constexpr size_t B_pack = rndB(B_cnt  + (size_t)kB*kNB*4);               // u64 [2*3072]
constexpr size_t B_key  = rndB(B_pack + (size_t)kB*kNA*8);
constexpr size_t B_nidx = rndB(B_key  + (size_t)kB*kNA*4);
constexpr size_t B_mrg  = rndB(B_nidx + (size_t)kB*kNA*4);
constexpr size_t B_slot = rndB(B_mrg  + (size_t)kB*kNA*4);
constexpr size_t B_unml = rndB(B_slot + (size_t)kB*kNA*4);
constexpr size_t B_ucnt = rndB(B_unml + (size_t)kB*kNB*4);
constexpr size_t B_aidx = rndB(B_ucnt + 64);

// ---------------- small setup kernels ----------------
__global__ void k_idx(int* __restrict__ a_idx){
  int t = blockIdx.x*256 + threadIdx.x;
  if (t >= kN) return;
  int h = t>>6, w = t&63;
  if ((h|w)&1) a_idx[d_arank(h,w)] = t;
}
__global__ void k_init(unsigned long long* __restrict__ pack, int* __restrict__ ucnt){
  int i = blockIdx.x*256 + threadIdx.x;
  if (i < kB*kNA) pack[i] = 0ull;
  if (i < kB) ucnt[i] = 0;
}
__global__ void k_gather(const float* __restrict__ net, float* __restrict__ mA, float* __restrict__ mB){
  int blk = blockIdx.x; int b = blk >> 12; int t = blk & 4095;
  int lane = threadIdx.x;
  const float* xp = net + ((size_t)b*kN + t)*kC;
  float v[5]; float s2 = 0.f;
  #pragma unroll
  for (int i=0;i<5;i++){ float f = xp[lane + i*64]; v[i]=f; s2 += f*f; }
  s2 = wave_sum(s2);
  float rn = 1.0f / sqrtf(s2);
  int h=t>>6, w=t&63;
  float* dp;
  if (!((h|w)&1)) dp = mB + ((size_t)b*kNB + ((h>>1)*32+(w>>1)))*kC;
  else            dp = mA + ((size_t)b*kNA + d_arank(h,w))*kC;
  #pragma unroll
  for (int i=0;i<5;i++) dp[lane + i*64] = v[i]*rn;
}

// ---------------- fused score GEMM (NT, exact fp32) + row argmax ----------------
__global__ __launch_bounds__(256) void k_scores(const float* __restrict__ mA, const float* __restrict__ mB,
                                                unsigned long long* __restrict__ pack){
  __shared__ __align__(16) float As[16][68];
  __shared__ __align__(16) float Bs[16][68];
  const int b = blockIdx.z;
  const int m0 = blockIdx.x*64, n0 = blockIdx.y*64;
  const int tid = threadIdx.x;
  const int mr = tid>>4, nc = tid&15;
  const int lr = tid>>2, lc4 = (tid&3)*4;
  const float* Ab = mA + (size_t)b*kNA*kC;
  const float* Bb = mB + (size_t)b*kNB*kC;
  float acc[4][4] = {};
  for (int k0=0; k0<kC; k0+=16){
    __syncthreads();
    {
      float4 av = *reinterpret_cast<const float4*>(&Ab[(size_t)(m0+lr)*kC + k0 + lc4]);
      As[lc4+0][lr]=av.x; As[lc4+1][lr]=av.y; As[lc4+2][lr]=av.z; As[lc4+3][lr]=av.w;
      float4 bv = *reinterpret_cast<const float4*>(&Bb[(size_t)(n0+lr)*kC + k0 + lc4]);
      Bs[lc4+0][lr]=bv.x; Bs[lc4+1][lr]=bv.y; Bs[lc4+2][lr]=bv.z; Bs[lc4+3][lr]=bv.w;
    }
    __syncthreads();
    #pragma unroll
    for (int kk=0;kk<16;kk++){
      const float4 a4 = *reinterpret_cast<const float4*>(&As[kk][mr*4]);
      const float4 b4 = *reinterpret_cast<const float4*>(&Bs[kk][nc*4]);
      const float aa[4]={a4.x,a4.y,a4.z,a4.w};
      const float bb[4]={b4.x,b4.y,b4.z,b4.w};
      #pragma unroll
      for (int i=0;i<4;i++)
        #pragma unroll
        for (int j=0;j<4;j++)
          acc[i][j] = fmaf(aa[i], bb[j], acc[i][j]);
    }
  }
  #pragma unroll
  for (int i=0;i<4;i++){
    float bs = acc[i][0]; int bj = n0 + nc*4;
    #pragma unroll
    for (int j=1;j<4;j++){
      float v = acc[i][j];
      if (v > bs){ bs=v; bj=n0+nc*4+j; }
    }
    #pragma unroll
    for (int off=1; off<16; off<<=1){
      float os = __shfl_xor(bs, off, 16);
      int   oj = __shfl_xor(bj, off, 16);
      if (os > bs || (os == bs && oj < bj)){ bs=os; bj=oj; }
    }
    if (nc == 0){
      unsigned int u = __float_as_uint(bs);
      unsigned int key = (u & 0x80000000u) ? ~u : (u | 0x80000000u);
      unsigned long long pk = ((unsigned long long)key << 32) |
                              (unsigned long long)(0xFFFFFFFFu - (unsigned int)bj);
      atomicMax(&pack[(size_t)b*kNA + m0 + mr*4 + i], pk);
    }
  }
}
__global__ void k_decode(const unsigned long long* __restrict__ pack, unsigned int* __restrict__ nmkey,
                         int* __restrict__ node_idx){
  int i = blockIdx.x*256 + threadIdx.x;
  if (i >= kB*kNA) return;
  unsigned long long p = pack[i];
  nmkey[i]    = (unsigned int)(p>>32);
  node_idx[i] = (int)(0xFFFFFFFFu - (unsigned int)(p & 0xFFFFFFFFull));
}
__global__ __launch_bounds__(256) void k_rank(const unsigned int* __restrict__ nmkey, int* __restrict__ merged,
                                              int* __restrict__ slot_of, int* __restrict__ unm_list,
                                              int* __restrict__ ucnt){
  __shared__ unsigned int keys[kNA];
  int b = blockIdx.y;
  int i = blockIdx.x*256 + threadIdx.x;
  const unsigned int* kb = nmkey + (size_t)b*kNA;
  for (int idx=threadIdx.x; idx<kNA; idx+=256) keys[idx] = kb[idx];
  __syncthreads();
  unsigned int ki = keys[i];
  int rank = 0;
  for (int j=0;j<kNA;j++){
    unsigned int kj = keys[j];
    rank += (kj > ki) || (kj == ki && j < i);
  }
  int mg = rank < kR;
  merged[(size_t)b*kNA + i] = mg;
  if (!mg){
    int s = atomicAdd(&ucnt[b], 1);
    unm_list[(size_t)b*kNB + s] = i;
    slot_of[(size_t)b*kNA + i] = s;
  }
}

// ---------------- layernorm (OB: bf16 out) ----------------
template<bool OB>
__global__ void k_ln(const float* __restrict__ x, const float* __restrict__ g,
                     const float* __restrict__ be, void* __restrict__ yv){
  const int row = blockIdx.x;
  const int lane = threadIdx.x;
  const float* xp = x + (size_t)row*kC;
  float v[5]; float s=0.f, s2=0.f;
  #pragma unroll
  for (int i=0;i<5;i++){ float f = xp[lane + i*64]; v[i]=f; s+=f; s2+=f*f; }
  s = wave_sum(s); s2 = wave_sum(s2);
  float mu = s * (1.0f/kC);
  float var = s2 * (1.0f/kC) - mu*mu;
  float rstd = rsqrtf(var + 1e-5f);
  #pragma unroll
  for (int i=0;i<5;i++){
    int c = lane + i*64;
    float o = (v[i]-mu)*rstd*g[c] + be[c];
    if (OB) ((unsigned short*)yv)[(size_t)row*kC + c] = f2b(o);
    else    ((float*)yv)[(size_t)row*kC + c] = o;
  }
}

// ---------------- merge ----------------
__global__ void k_merge_unm(const float* __restrict__ y, const int* __restrict__ a_idx,
                            const int* __restrict__ unm_list, float* __restrict__ xm){
  int blk = blockIdx.x; int b = blk >> 10; int s = blk & 1023;
  int i = unm_list[(size_t)b*kNB + s];
  int t = a_idx[i];
  const float* sp = y + ((size_t)b*kN + t)*kC;
  float* dp = xm + ((size_t)b*kNM + s)*kC;
  int lane = threadIdx.x;
  #pragma unroll
  for (int q=0;q<5;q++) dp[lane+q*64] = sp[lane+q*64];
}
__global__ void k_merge_dst(const float* __restrict__ y, float* __restrict__ xm, float* __restrict__ cnt){
  int blk = blockIdx.x; int b = blk >> 10; int j = blk & 1023;
  int t = 128*(j>>5) + 2*(j&31);
  const float* sp = y + ((size_t)b*kN + t)*kC;
  float* dp = xm + ((size_t)b*kNM + kNB + j)*kC;
  int lane = threadIdx.x;
  #pragma unroll
  for (int q=0;q<5;q++) dp[lane+q*64] = sp[lane+q*64];
  if (lane==0) cnt[(size_t)b*kNB + j] = 1.0f;
}
__global__ void k_merge_src(const float* __restrict__ y, const int* __restrict__ a_idx,
                            const int* __restrict__ merged, const int* __restrict__ node_idx,
                            float* __restrict__ xm, float* __restrict__ cnt){
  int blk = blockIdx.x; int b = blk / kNA; int i = blk % kNA;
  if (!merged[(size_t)b*kNA + i]) return;
  int t = a_idx[i]; int j = node_idx[(size_t)b*kNA + i];
  const float* sp = y + ((size_t)b*kN + t)*kC;
  float* dp = xm + ((size_t)b*kNM + kNB + j)*kC;
  int lane = threadIdx.x;
  #pragma unroll
  for (int q=0;q<5;q++) atomicAdd(&dp[lane+q*64], sp[lane+q*64]);
  if (lane==0) atomicAdd(&cnt[(size_t)b*kNB + j], 1.0f);
}
__global__ void k_merge_scale(float* __restrict__ xm, const float* __restrict__ cnt){
  int blk = blockIdx.x; int b = blk >> 10; int j = blk & 1023;
  float inv = 1.0f / cnt[(size_t)b*kNB + j];
  float* dp = xm + ((size_t)b*kNM + kNB + j)*kC;
  int lane = threadIdx.x;
  #pragma unroll
  for (int q=0;q<5;q++) dp[lane+q*64] *= inv;
}

// ---------------- weight transpose + bf16 convert: W[K x N] -> Wt[N x K] ----------------
__global__ __launch_bounds__(256) void k_wt(const float* __restrict__ W, unsigned short* __restrict__ Wt,
                                            int K, int N){
  __shared__ float tile[64][65];
  int k0 = blockIdx.x*64, n0 = blockIdx.y*64;
  int tid = threadIdx.x;
  #pragma unroll
  for (int l=0;l<16;l++){
    int e = tid + l*256; int r = e>>6, c = e&63;
    int gk = k0+r, gn = n0+c;
    tile[r][c] = (gk<K && gn<N) ? W[(size_t)gk*N+gn] : 0.f;
  }
  __syncthreads();
  #pragma unroll
  for (int l=0;l<16;l++){
    int e = tid + l*256; int r = e>>6, c = e&63;
    int gn = n0+r, gk = k0+c;
    if (gn<N && gk<K) Wt[(size_t)gn*K+gk] = f2b(tile[c][r]);
  }
}
__global__ void k_f2b(const float* __restrict__ x, unsigned short* __restrict__ y, int n){
  int i = blockIdx.x*256 + threadIdx.x;
  if (i<n) y[i] = f2b(x[i]);
}

// ---------------- bf16 MFMA GEMM: out[MxN] = A[MxK] @ Bt[NxK]^T (+bias)(+resid) ----------------
template<typename OT, bool BIAS, bool RES>
__global__ __launch_bounds__(256) void k_bgemm(const unsigned short* __restrict__ A,
    const unsigned short* __restrict__ Bt, const float* __restrict__ bias,
    const float* __restrict__ resid, OT* __restrict__ out, int M, int N, int K){
  constexpr int LDK = 72;
  __shared__ unsigned short As[128*LDK];
  __shared__ unsigned short Bs[128*LDK];
  const int tid = threadIdx.x;
  const int m0 = blockIdx.x*128, n0 = blockIdx.y*128;
  const int wid = tid>>6, lane = tid&63;
  const int wm = (wid>>1)*64, wn = (wid&1)*64;
  const int lr = lane&15, quad = lane>>4;
  const f32x4 zero4 = {0.f,0.f,0.f,0.f};
  f32x4 acc[4][4];
  #pragma unroll
  for (int i=0;i<4;i++)
    #pragma unroll
    for (int j=0;j<4;j++) acc[i][j] = zero4;
  for (int k0=0; k0<K; k0+=64){
    __syncthreads();
    #pragma unroll
    for (int l=0;l<4;l++){
      int e = tid + l*256;
      int row = e>>3, seg = (e&7)*8;
      int gm = m0+row;
      uint4 va = (gm<M) ? *reinterpret_cast<const uint4*>(&A[(size_t)gm*K + k0 + seg])
                        : make_uint4(0u,0u,0u,0u);
      *reinterpret_cast<uint4*>(&As[row*LDK + seg]) = va;
      int gn = n0+row;
      uint4 vb = (gn<N) ? *reinterpret_cast<const uint4*>(&Bt[(size_t)gn*K + k0 + seg])
                        : make_uint4(0u,0u,0u,0u);
      *reinterpret_cast<uint4*>(&Bs[row*LDK + seg]) = vb;
    }
    __syncthreads();
    #pragma unroll
    for (int kk=0; kk<64; kk+=32){
      bf16x8 af[4], bfr[4];
      #pragma unroll
      for (int i=0;i<4;i++) af[i]  = *reinterpret_cast<const bf16x8*>(&As[(wm+i*16+lr)*LDK + kk + quad*8]);
      #pragma unroll
      for (int j=0;j<4;j++) bfr[j] = *reinterpret_cast<const bf16x8*>(&Bs[(wn+j*16+lr)*LDK + kk + quad*8]);
      #pragma unroll
      for (int i=0;i<4;i++)
        #pragma unroll
        for (int j=0;j<4;j++)
          acc[i][j] = __builtin_amdgcn_mfma_f32_16x16x32_bf16(af[i], bfr[j], acc[i][j], 0, 0, 0);
    }
  }
  #pragma unroll
  for (int i=0;i<4;i++){
    #pragma unroll
    for (int j=0;j<4;j++){
      int gn = n0 + wn + j*16 + lr;
      if (gn >= N) continue;
      float bv = BIAS ? bias[gn] : 0.f;
      #pragma unroll
      for (int r=0;r<4;r++){
        int gm = m0 + wm + i*16 + quad*4 + r;
        if (gm >= M) continue;
        float v = acc[i][j][r] + bv;
        if (RES) v += resid[(size_t)gm*N + gn];
        if constexpr (sizeof(OT)==2) out[(size_t)gm*N + gn] = (OT)f2b(v);
        else                         out[(size_t)gm*N + gn] = (OT)v;
      }
    }
  }
}

// ---------------- GEGLU elementwise: G = H[:, :1280] * gelu(H[:, 1280:]) ----------------
__global__ void k_geglu(const unsigned short* __restrict__ H, unsigned short* __restrict__ G){
  int e = blockIdx.x*256 + threadIdx.x;   // 8192*160 threads
  int m = e/160, t = e - m*160;
  const unsigned short* hp = H + (size_t)m*2560 + t*8;
  uint4 xv = *reinterpret_cast<const uint4*>(hp);
  uint4 gv = *reinterpret_cast<const uint4*>(hp + 1280);
  const unsigned short* xu = reinterpret_cast<const unsigned short*>(&xv);
  const unsigned short* gu = reinterpret_cast<const unsigned short*>(&gv);
  unsigned short ov[8];
  #pragma unroll
  for (int d=0; d<8; d++){
    float x = b2f(xu[d]);
    float g = b2f(gu[d]);
    float ge = 0.5f*g*(1.0f + erff(g*0.70710678118654752f));
    ov[d] = f2b(x*ge);
  }
  *reinterpret_cast<uint4*>(G + (size_t)m*1280 + t*8) = *reinterpret_cast<const uint4*>(ov);
}

// ---------------- attention ----------------
// flash self-attn, bf16 I/O, fp32 math. QKV row stride 960 (Q|K|V fused).
__global__ __launch_bounds__(256) void k_attn1(const unsigned short* __restrict__ QKV,
                                               unsigned short* __restrict__ Oa){
  __shared__ __align__(16) float Qt[kDH][68];
  __shared__ __align__(16) float Kt[kDH][68];
  __shared__ __align__(16) float Vt[kDH][68];
  __shared__ __align__(16) float Ps[64][68];
  __shared__ float alpha_s[64];
  __shared__ float ls[64];
  const int b = blockIdx.z, hh = blockIdx.y;
  const int q0 = blockIdx.x*64;
  const int tid = threadIdx.x;
  const int mr = tid>>4, nc = tid&15;
  const int r2 = tid>>2, cg = tid&3, c0 = cg*10;
  const float scale = 0.15811388300841898f;
  const unsigned short* Qb = QKV + ((size_t)b*kNM + q0)*960 + hh*kDH;
  const unsigned short* Kb = QKV + ((size_t)b*kNM)*960 + 320 + hh*kDH;
  const unsigned short* Vb = QKV + ((size_t)b*kNM)*960 + 640 + hh*kDH;
  for (int e = tid; e < 320; e += 256){
    int row = e/5, c8 = (e - row*5)*8;
    uint4 v = *reinterpret_cast<const uint4*>(Qb + (size_t)row*960 + c8);
    const unsigned short* u = reinterpret_cast<const unsigned short*>(&v);
    #pragma unroll
    for (int d=0;d<8;d++) Qt[c8+d][row] = b2f(u[d]);
  }
  float m_i[4], l_i[4], oacc[10];
  #pragma unroll
  for (int i=0;i<4;i++){ m_i[i] = -1e30f; l_i[i] = 0.f; }
  #pragma unroll
  for (int j=0;j<10;j++) oacc[j] = 0.f;
  for (int kt = 0; kt < kNM; kt += 64){
    __syncthreads();
    for (int e = tid; e < 320; e += 256){
      int row = e/5, c8 = (e - row*5)*8;
      uint4 v = *reinterpret_cast<const uint4*>(Kb + (size_t)(kt+row)*960 + c8);
      const unsigned short* u = reinterpret_cast<const unsigned short*>(&v);
      #pragma unroll
      for (int d=0;d<8;d++) Kt[c8+d][row] = b2f(u[d]);
      uint4 w = *reinterpret_cast<const uint4*>(Vb + (size_t)(kt+row)*960 + c8);
      const unsigned short* uw = reinterpret_cast<const unsigned short*>(&w);
      #pragma unroll
      for (int d=0;d<8;d++) Vt[c8+d][row] = b2f(uw[d]);
    }
    __syncthreads();
    float acc[4][4] = {};
    #pragma unroll 8
    for (int k=0;k<kDH;k++){
      const float4 q4 = *reinterpret_cast<const float4*>(&Qt[k][mr*4]);
      const float4 k4 = *reinterpret_cast<const float4*>(&Kt[k][nc*4]);
      const float qa[4]={q4.x,q4.y,q4.z,q4.w};
      const float ka[4]={k4.x,k4.y,k4.z,k4.w};
      #pragma unroll
      for (int i=0;i<4;i++)
        #pragma unroll
        for (int j=0;j<4;j++)
          acc[i][j] = fmaf(qa[i], ka[j], acc[i][j]);
    }
    #pragma unroll
    for (int i=0;i<4;i++){
      float s0=acc[i][0]*scale, s1=acc[i][1]*scale, s2=acc[i][2]*scale, s3=acc[i][3]*scale;
      float rm = fmaxf(fmaxf(s0,s1), fmaxf(s2,s3));
      #pragma unroll
      for (int off=1; off<16; off<<=1) rm = fmaxf(rm, __shfl_xor(rm, off, 64));
      float mnew = fmaxf(m_i[i], rm);
      float alpha = __expf(m_i[i] - mnew);
      float p0=__expf(s0-mnew), p1=__expf(s1-mnew), p2=__expf(s2-mnew), p3=__expf(s3-mnew);
      float psum = p0+p1+p2+p3;
      #pragma unroll
      for (int off=1; off<16; off<<=1) psum += __shfl_xor(psum, off, 64);
      l_i[i] = l_i[i]*alpha + psum;
      m_i[i] = mnew;
      int r = mr*4 + i;
      *reinterpret_cast<float4*>(&Ps[r][nc*4]) = make_float4(p0,p1,p2,p3);
      if (nc==0) alpha_s[r] = alpha;
    }
    __syncthreads();
    float av = alpha_s[r2];
    #pragma unroll
    for (int j=0;j<10;j++) oacc[j] *= av;
    for (int kk=0; kk<64; kk+=4){
      const float4 p = *reinterpret_cast<const float4*>(&Ps[r2][kk]);
      #pragma unroll
      for (int j=0;j<10;j++){
        const float4 v = *reinterpret_cast<const float4*>(&Vt[c0+j][kk]);
        oacc[j] += p.x*v.x + p.y*v.y + p.z*v.z + p.w*v.w;
      }
    }
  }
  if (nc==0){
    #pragma unroll
    for (int i=0;i<4;i++) ls[mr*4+i] = l_i[i];
  }
  __syncthreads();
  float inv = 1.0f / ls[r2];
  unsigned short* Ob = Oa + ((size_t)b*kNM + q0 + r2)*kC + hh*kDH + c0;
  #pragma unroll
  for (int j=0;j<10;j++) Ob[j] = f2b(oacc[j]*inv);
}

// cross-attn: bf16 I/O. KV row stride 640 (K|V fused).
__global__ __launch_bounds__(1024) void k_attn2(const unsigned short* __restrict__ Q,
                                                const unsigned short* __restrict__ KV,
                                                unsigned short* __restrict__ Oa){
  __shared__ float Ks[kLC][41];
  __shared__ float Vs[kLC][41];
  __shared__ float qs[16][41];
  __shared__ float ps[16][80];
  const int b = blockIdx.z, hh = blockIdx.y;
  const int tid = threadIdx.x, wv = tid>>6, lane = tid&63;
  const int hoff = hh*kDH;
  for (int e=tid; e<kLC*kDH; e+=1024){
    int kk = e/kDH, d = e - kk*kDH;
    size_t off = ((size_t)b*kLC + kk)*640 + hoff + d;
    Ks[kk][d] = b2f(KV[off]);
    Vs[kk][d] = b2f(KV[off + 320]);
  }
  const int q = blockIdx.x*16 + wv;
  if (lane < kDH) qs[wv][lane] = b2f(Q[((size_t)b*kN + q)*kC + hoff + lane]);
  __syncthreads();
  const bool has2 = (lane + 64) < kLC;
  const int k2i = has2 ? lane+64 : 0;
  float s0=0.f, s1=0.f;
  #pragma unroll
  for (int d=0; d<kDH; d++){
    float qd = qs[wv][d];
    s0 = fmaf(qd, Ks[lane][d], s0);
    s1 = fmaf(qd, Ks[k2i][d], s1);
  }
  s0 *= 0.15811388300841898f;
  s1 = has2 ? s1*0.15811388300841898f : -1e30f;
  float mx = wave_max(fmaxf(s0, s1));
  float p0 = __expf(s0-mx);
  float p1 = has2 ? __expf(s1-mx) : 0.f;
  ps[wv][lane] = p0;
  if (has2) ps[wv][64+lane] = p1;
  float l = wave_sum(p0+p1);
  if (lane < kDH){
    float acc = 0.f;
    #pragma unroll
    for (int k3=0;k3<kLC;k3++) acc = fmaf(ps[wv][k3], Vs[k3][lane], acc);
    Oa[((size_t)b*kN + q)*kC + hoff + lane] = f2b(acc / l);
  }
}

// ---------------- unmerge + residual ----------------
__global__ void k_unmerge(const float* __restrict__ net, const float* __restrict__ Xo,
                          const int* __restrict__ merged, const int* __restrict__ node_idx,
                          const int* __restrict__ slot_of, float* __restrict__ net1){
  int blk = blockIdx.x; int b = blk >> 12; int t = blk & 4095;
  int h = t>>6, w = t&63;
  int row;
  if (!((h|w)&1)) row = kNB + ((h>>1)*32 + (w>>1));
  else {
    int i = d_arank(h,w);
    row = merged[(size_t)b*kNA+i] ? (kNB + node_idx[(size_t)b*kNA+i]) : slot_of[(size_t)b*kNA+i];
  }
  const float* np_ = net + ((size_t)b*kN + t)*kC;
  const float* xp = Xo + ((size_t)b*kNM + row)*kC;
  float* op = net1 + ((size_t)b*kN + t)*kC;
  int lane = threadIdx.x;
  #pragma unroll
  for (int q=0;q<5;q++){ int c = lane+q*64; op[c] = np_[c] + xp[c]; }
}

// ---------------- launch ----------------
extern "C" void kernel_launch(void* const* d_in, const int* in_sizes, int n_in,
                              void* d_out, int out_size, void* d_ws, size_t ws_size,
                              hipStream_t stream){
  const float* net = (const float*)d_in[0];
  const float* ctx = (const float*)d_in[1];
  const float* ln1g=(const float*)d_in[2], *ln1b=(const float*)d_in[3];
  const float* ln2g=(const float*)d_in[4], *ln2b=(const float*)d_in[5];
  const float* ln3g=(const float*)d_in[6], *ln3b=(const float*)d_in[7];
  const float* w1q=(const float*)d_in[8],  *w1k=(const float*)d_in[9];
  const float* w1v=(const float*)d_in[10], *w1o=(const float*)d_in[11];
  const float* b1o=(const float*)d_in[12];
  const float* w2q=(const float*)d_in[13], *w2k=(const float*)d_in[14];
  const float* w2v=(const float*)d_in[15], *w2o=(const float*)d_in[16];
  const float* b2o=(const float*)d_in[17];
  const float* fw1=(const float*)d_in[18], *fb1=(const float*)d_in[19];
  const float* fw2=(const float*)d_in[20], *fb2=(const float*)d_in[21];

  char* ws = (char*)d_ws;
  float* mnA  = (float*)(ws + B_mnA);
  float* mnB  = (float*)(ws + B_mnB);
  float* y32  = (float*)(ws + B_y32);
  float* xm32 = (float*)(ws + B_xm);
  float* Xo1  = (float*)(ws + B_xo1);
  float* net1 = (float*)(ws + B_net1);
  float* net2 = (float*)(ws + B_net2);
  float* cnt  = (float*)(ws + B_cnt);
  unsigned short* Hb   = (unsigned short*)(ws + B_H);
  unsigned short* Gb   = (unsigned short*)(ws + B_G);
  unsigned short* QKVb = (unsigned short*)(ws + B_QKVb);
  unsigned short* yb   = (unsigned short*)(ws + B_yb);
  unsigned short* xmb  = (unsigned short*)(ws + B_xmb);
  unsigned short* Ao1b = (unsigned short*)(ws + B_Ao1b);
  unsigned short* Q2b  = (unsigned short*)(ws + B_Q2b);
  unsigned short* Ao2b = (unsigned short*)(ws + B_Ao2b);
  unsigned short* KV2b = (unsigned short*)(ws + B_KV2b);
  unsigned short* ctxb = (unsigned short*)(ws + B_ctxb);
  unsigned short* Wqkv = (unsigned short*)(ws + B_Wqkv);
  unsigned short* Wo1  = (unsigned short*)(ws + B_Wo1);
  unsigned short* Wq2  = (unsigned short*)(ws + B_Wq2);
  unsigned short* Wkv2 = (unsigned short*)(ws + B_Wkv2);
  unsigned short* Wo2  = (unsigned short*)(ws + B_Wo2);
  unsigned short* Wff1 = (unsigned short*)(ws + B_Wff1);
  unsigned short* Wff2 = (unsigned short*)(ws + B_Wff2);
  unsigned long long* pack = (unsigned long long*)(ws + B_pack);
  unsigned int* nmkey = (unsigned int*)(ws + B_key);
  int* nidx = (int*)(ws + B_nidx); int* mrg = (int*)(ws + B_mrg); int* slot = (int*)(ws + B_slot);
  int* unml = (int*)(ws + B_unml); int* ucnt = (int*)(ws + B_ucnt); int* aidx = (int*)(ws + B_aidx);

  // --- weight conversion (transpose to [N x K] bf16) ---
  k_wt<<<dim3(5,5),   256, 0, stream>>>(w1q, Wqkv,             320, 320);
  k_wt<<<dim3(5,5),   256, 0, stream>>>(w1k, Wqkv + 320*320,   320, 320);
  k_wt<<<dim3(5,5),   256, 0, stream>>>(w1v, Wqkv + 640*320,   320, 320);
  k_wt<<<dim3(5,5),   256, 0, stream>>>(w1o, Wo1,              320, 320);
  k_wt<<<dim3(5,5),   256, 0, stream>>>(w2q, Wq2,              320, 320);
  k_wt<<<dim3(12,5),  256, 0, stream>>>(w2k, Wkv2,             768, 320);
  k_wt<<<dim3(12,5),  256, 0, stream>>>(w2v, Wkv2 + 320*768,   768, 320);
  k_wt<<<dim3(5,5),   256, 0, stream>>>(w2o, Wo2,              320, 320);
  k_wt<<<dim3(5,40),  256, 0, stream>>>(fw1, Wff1,             320, 2560);
  k_wt<<<dim3(20,5),  256, 0, stream>>>(fw2, Wff2,             1280, 320);
  k_f2b<<<(kB*kLC*kDC+255)/256, 256, 0, stream>>>(ctx, ctxb, kB*kLC*kDC);

  // --- ToMe indices (exact fp32) ---
  k_idx   <<<16, 256, 0, stream>>>(aidx);
  k_init  <<<(kB*kNA+255)/256, 256, 0, stream>>>(pack, ucnt);
  k_gather<<<kB*kN, 64, 0, stream>>>(net, mnA, mnB);
  k_scores<<<dim3(kNA/64, kNB/64, kB), 256, 0, stream>>>(mnA, mnB, pack);
  k_decode<<<(kB*kNA+255)/256, 256, 0, stream>>>(pack, nmkey, nidx);
  k_rank  <<<dim3(kNA/256, kB), 256, 0, stream>>>(nmkey, mrg, slot, unml, ucnt);
  // --- merge(LN1(net)) ---
  k_ln<false><<<kB*kN, 64, 0, stream>>>(net, ln1g, ln1b, y32);
  k_merge_unm  <<<kB*kNB, 64, 0, stream>>>(y32, aidx, unml, xm32);
  k_merge_dst  <<<kB*kNB, 64, 0, stream>>>(y32, xm32, cnt);
  k_merge_src  <<<kB*kNA, 64, 0, stream>>>(y32, aidx, mrg, nidx, xm32, cnt);
  k_merge_scale<<<kB*kNB, 64, 0, stream>>>(xm32, cnt);
  k_f2b<<<(kB*kNM*kC+255)/256, 256, 0, stream>>>(xm32, xmb, kB*kNM*kC);
  // --- attn1 (self, merged seq) ---
  k_bgemm<unsigned short,false,false><<<dim3(32,8), 256, 0, stream>>>(xmb, Wqkv, nullptr, nullptr, QKVb, 4096, 960, 320);
  k_attn1<<<dim3(kNM/64, kH, kB), 256, 0, stream>>>(QKVb, Ao1b);
  k_bgemm<float,true,false><<<dim3(32,3), 256, 0, stream>>>(Ao1b, Wo1, b1o, nullptr, Xo1, 4096, 320, 320);
  k_unmerge<<<kB*kN, 64, 0, stream>>>(net, Xo1, mrg, nidx, slot, net1);
  // --- attn2 (cross) ---
  k_ln<true><<<kB*kN, 64, 0, stream>>>(net1, ln2g, ln2b, yb);
  k_bgemm<unsigned short,false,false><<<dim3(64,3), 256, 0, stream>>>(yb, Wq2, nullptr, nullptr, Q2b, 8192, 320, 320);
  k_bgemm<unsigned short,false,false><<<dim3(2,5), 256, 0, stream>>>(ctxb, Wkv2, nullptr, nullptr, KV2b, 154, 640, 768);
  k_attn2<<<dim3(kN/16, kH, kB), 1024, 0, stream>>>(Q2b, KV2b, Ao2b);
  k_bgemm<float,true,true><<<dim3(64,3), 256, 0, stream>>>(Ao2b, Wo2, b2o, net1, net2, 8192, 320, 320);
  // --- GEGLU FF ---
  k_ln<true><<<kB*kN, 64, 0, stream>>>(net2, ln3g, ln3b, yb);
  k_bgemm<unsigned short,true,false><<<dim3(64,20), 256, 0, stream>>>(yb, Wff1, fb1, nullptr, Hb, 8192, 2560, 320);
  k_geglu<<<(kB*kN*160+255)/256, 256, 0, stream>>>(Hb, Gb);
  k_bgemm<float,true,true><<<dim3(64,3), 256, 0, stream>>>(Gb, Wff2, fb2, net2, (float*)d_out, 8192, 320, 1280);
}

// Round 5
// 759.183 us; speedup vs baseline: 2.3093x; 1.2579x over previous
//
#include <hip/hip_runtime.h>

typedef __attribute__((ext_vector_type(8))) short bf16x8;
typedef __attribute__((ext_vector_type(4))) float f32x4;

// ---------------- problem constants ----------------
constexpr int kB   = 2;
constexpr int kN   = 4096;   // tokens (64x64)
constexpr int kC   = 320;    // channels
constexpr int kNA  = 3072;   // src (non-dst) tokens
constexpr int kNB  = 1024;   // dst tokens
constexpr int kNM  = 2048;   // merged seq len
constexpr int kR   = 2048;   // merged src count
constexpr int kH   = 8;
constexpr int kDH  = 40;
constexpr int kLC  = 77;
constexpr int kDC  = 768;
constexpr int kDFF = 1280;

__device__ __forceinline__ unsigned short f2b(float f){
  unsigned u = __float_as_uint(f);
  u += 0x7FFF + ((u>>16)&1);
  return (unsigned short)(u>>16);
}
__device__ __forceinline__ float b2f(unsigned short h){ return __uint_as_float(((unsigned)h)<<16); }

__device__ __forceinline__ float wave_sum(float v){
  #pragma unroll
  for (int m=32;m>=1;m>>=1) v += __shfl_xor(v, m, 64);
  return v;
}
__device__ __forceinline__ float wave_max(float v){
  #pragma unroll
  for (int m=32;m>=1;m>>=1) v = fmaxf(v, __shfl_xor(v, m, 64));
  return v;
}
__device__ __forceinline__ int d_arank(int h, int w){
  int base = 32*((h+1)>>1) + 64*(h>>1);
  return base + ((h&1) ? w : (w>>1));
}

// ---------------- ws layout (byte offsets) ----------------
constexpr size_t rndB(size_t x){ return (x + 255) & ~(size_t)255; }
constexpr size_t B_mnA  = 0;                                             // fp32 [2*3072*320]
constexpr size_t B_mnB  = rndB(B_mnA + (size_t)kB*kNA*kC*4);             // fp32 [2*1024*320]
constexpr size_t B_y32  = rndB(B_mnB + (size_t)kB*kNB*kC*4);             // fp32 [2*4096*320] (LN1)
constexpr size_t B_xm   = rndB(B_y32 + (size_t)kB*kN*kC*4);              // fp32 [2*2048*320]
constexpr size_t B_xo1  = rndB(B_xm  + (size_t)kB*kNM*kC*4);             // fp32 [2*2048*320]
constexpr size_t B_net1 = rndB(B_xo1 + (size_t)kB*kNM*kC*4);             // fp32 [2*4096*320]
constexpr size_t B_H    = 0;  // bf16 [8192*2560] overlays mnA..net1 (41.94 MB, all dead by then)
constexpr size_t B_net2 = rndB(B_net1 + (size_t)kB*kN*kC*4);             // fp32 [2*4096*320]
constexpr size_t B_G    = rndB(B_net2 + (size_t)kB*kN*kC*4);             // bf16 [8192*1280]
constexpr size_t B_QKVb = rndB(B_G    + (size_t)kB*kN*kDFF*2);           // bf16 [4096*960]
constexpr size_t B_yb   = rndB(B_QKVb + (size_t)kB*kNM*960*2);           // bf16 [8192*320]
constexpr size_t B_xmb  = rndB(B_yb   + (size_t)kB*kN*kC*2);             // bf16 [4096*320]
constexpr size_t B_Ao1b = rndB(B_xmb  + (size_t)kB*kNM*kC*2);            // bf16 [4096*320]
constexpr size_t B_Q2b  = rndB(B_Ao1b + (size_t)kB*kNM*kC*2);            // bf16 [8192*320]
constexpr size_t B_Ao2b = rndB(B_Q2b  + (size_t)kB*kN*kC*2);             // bf16 [8192*320]
constexpr size_t B_KV2b = rndB(B_Ao2b + (size_t)kB*kN*kC*2);             // bf16 [154*640]
constexpr size_t B_ctxb = rndB(B_KV2b + (size_t)kB*kLC*640*2);           // bf16 [154*768]
constexpr size_t B_Wqkv = rndB(B_ctxb + (size_t)kB*kLC*kDC*2);           // bf16 [960*320]
constexpr size_t B_Wo1  = rndB(B_Wqkv + (size_t)960*320*2);              // bf16 [320*320]
constexpr size_t B_Wq2  = rndB(B_Wo1  + (size_t)320*320*2);
constexpr size_t B_Wkv2 = rndB(B_Wq2  + (size_t)320*320*2);              // bf16 [640*768]
constexpr size_t B_Wo2  = rndB(B_Wkv2 + (size_t)640*768*2);
constexpr size_t B_Wff1 = rndB(B_Wo2  + (size_t)320*320*2);              // bf16 [2560*320]
constexpr size_t B_Wff2 = rndB(B_Wff1 + (size_t)2560*320*2);             // bf16 [320*1280]
constexpr size_t B_cnt  = rndB(B_Wff2 + (size_t)320*1280*2);             // fp32 [2*1024]
constexpr size_t B_pack = rndB(B_cnt  + (size_t)kB*kNB*4);               // u64 [2*3072]
constexpr size_t B_key  = rndB(B_pack + (size_t)kB*kNA*8);
constexpr size_t B_nidx = rndB(B_key  + (size_t)kB*kNA*4);
constexpr size_t B_mrg  = rndB(B_nidx + (size_t)kB*kNA*4);
constexpr size_t B_slot = rndB(B_mrg  + (size_t)kB*kNA*4);
constexpr size_t B_unml = rndB(B_slot + (size_t)kB*kNA*4);
constexpr size_t B_ucnt = rndB(B_unml + (size_t)kB*kNB*4);
constexpr size_t B_aidx = rndB(B_ucnt + 64);

// ---------------- small setup kernels ----------------
__global__ void k_idx(int* __restrict__ a_idx){
  int t = blockIdx.x*256 + threadIdx.x;
  if (t >= kN) return;
  int h = t>>6, w = t&63;
  if ((h|w)&1) a_idx[d_arank(h,w)] = t;
}
__global__ void k_init(unsigned long long* __restrict__ pack, int* __restrict__ ucnt){
  int i = blockIdx.x*256 + threadIdx.x;
  if (i < kB*kNA) pack[i] = 0ull;
  if (i < kB) ucnt[i] = 0;
}
__global__ void k_gather(const float* __restrict__ net, float* __restrict__ mA, float* __restrict__ mB){
  int blk = blockIdx.x; int b = blk >> 12; int t = blk & 4095;
  int lane = threadIdx.x;
  const float* xp = net + ((size_t)b*kN + t)*kC;
  float v[5]; float s2 = 0.f;
  #pragma unroll
  for (int i=0;i<5;i++){ float f = xp[lane + i*64]; v[i]=f; s2 += f*f; }
  s2 = wave_sum(s2);
  float rn = 1.0f / sqrtf(s2);
  int h=t>>6, w=t&63;
  float* dp;
  if (!((h|w)&1)) dp = mB + ((size_t)b*kNB + ((h>>1)*32+(w>>1)))*kC;
  else            dp = mA + ((size_t)b*kNA + d_arank(h,w))*kC;
  #pragma unroll
  for (int i=0;i<5;i++) dp[lane + i*64] = v[i]*rn;
}

// ---------------- fused score GEMM (NT, exact fp32) + row argmax ----------------
__global__ __launch_bounds__(256) void k_scores(const float* __restrict__ mA, const float* __restrict__ mB,
                                                unsigned long long* __restrict__ pack){
  __shared__ __align__(16) float As[16][68];
  __shared__ __align__(16) float Bs[16][68];
  const int b = blockIdx.z;
  const int m0 = blockIdx.x*64, n0 = blockIdx.y*64;
  const int tid = threadIdx.x;
  const int mr = tid>>4, nc = tid&15;
  const int lr = tid>>2, lc4 = (tid&3)*4;
  const float* Ab = mA + (size_t)b*kNA*kC;
  const float* Bb = mB + (size_t)b*kNB*kC;
  float acc[4][4] = {};
  for (int k0=0; k0<kC; k0+=16){
    __syncthreads();
    {
      float4 av = *reinterpret_cast<const float4*>(&Ab[(size_t)(m0+lr)*kC + k0 + lc4]);
      As[lc4+0][lr]=av.x; As[lc4+1][lr]=av.y; As[lc4+2][lr]=av.z; As[lc4+3][lr]=av.w;
      float4 bv = *reinterpret_cast<const float4*>(&Bb[(size_t)(n0+lr)*kC + k0 + lc4]);
      Bs[lc4+0][lr]=bv.x; Bs[lc4+1][lr]=bv.y; Bs[lc4+2][lr]=bv.z; Bs[lc4+3][lr]=bv.w;
    }
    __syncthreads();
    #pragma unroll
    for (int kk=0;kk<16;kk++){
      const float4 a4 = *reinterpret_cast<const float4*>(&As[kk][mr*4]);
      const float4 b4 = *reinterpret_cast<const float4*>(&Bs[kk][nc*4]);
      const float aa[4]={a4.x,a4.y,a4.z,a4.w};
      const float bb[4]={b4.x,b4.y,b4.z,b4.w};
      #pragma unroll
      for (int i=0;i<4;i++)
        #pragma unroll
        for (int j=0;j<4;j++)
          acc[i][j] = fmaf(aa[i], bb[j], acc[i][j]);
    }
  }
  #pragma unroll
  for (int i=0;i<4;i++){
    float bs = acc[i][0]; int bj = n0 + nc*4;
    #pragma unroll
    for (int j=1;j<4;j++){
      float v = acc[i][j];
      if (v > bs){ bs=v; bj=n0+nc*4+j; }
    }
    #pragma unroll
    for (int off=1; off<16; off<<=1){
      float os = __shfl_xor(bs, off, 16);
      int   oj = __shfl_xor(bj, off, 16);
      if (os > bs || (os == bs && oj < bj)){ bs=os; bj=oj; }
    }
    if (nc == 0){
      unsigned int u = __float_as_uint(bs);
      unsigned int key = (u & 0x80000000u) ? ~u : (u | 0x80000000u);
      unsigned long long pk = ((unsigned long long)key << 32) |
                              (unsigned long long)(0xFFFFFFFFu - (unsigned int)bj);
      atomicMax(&pack[(size_t)b*kNA + m0 + mr*4 + i], pk);
    }
  }
}
__global__ void k_decode(const unsigned long long* __restrict__ pack, unsigned int* __restrict__ nmkey,
                         int* __restrict__ node_idx){
  int i = blockIdx.x*256 + threadIdx.x;
  if (i >= kB*kNA) return;
  unsigned long long p = pack[i];
  nmkey[i]    = (unsigned int)(p>>32);
  node_idx[i] = (int)(0xFFFFFFFFu - (unsigned int)(p & 0xFFFFFFFFull));
}
__global__ __launch_bounds__(256) void k_rank(const unsigned int* __restrict__ nmkey, int* __restrict__ merged,
                                              int* __restrict__ slot_of, int* __restrict__ unm_list,
                                              int* __restrict__ ucnt){
  __shared__ unsigned int keys[kNA];
  int b = blockIdx.y;
  int i = blockIdx.x*256 + threadIdx.x;
  const unsigned int* kb = nmkey + (size_t)b*kNA;
  for (int idx=threadIdx.x; idx<kNA; idx+=256) keys[idx] = kb[idx];
  __syncthreads();
  unsigned int ki = keys[i];
  int rank = 0;
  for (int j=0;j<kNA;j++){
    unsigned int kj = keys[j];
    rank += (kj > ki) || (kj == ki && j < i);
  }
  int mg = rank < kR;
  merged[(size_t)b*kNA + i] = mg;
  if (!mg){
    int s = atomicAdd(&ucnt[b], 1);
    unm_list[(size_t)b*kNB + s] = i;
    slot_of[(size_t)b*kNA + i] = s;
  }
}

// ---------------- layernorm (OB: bf16 out) ----------------
template<bool OB>
__global__ void k_ln(const float* __restrict__ x, const float* __restrict__ g,
                     const float* __restrict__ be, void* __restrict__ yv){
  const int row = blockIdx.x;
  const int lane = threadIdx.x;
  const float* xp = x + (size_t)row*kC;
  float v[5]; float s=0.f, s2=0.f;
  #pragma unroll
  for (int i=0;i<5;i++){ float f = xp[lane + i*64]; v[i]=f; s+=f; s2+=f*f; }
  s = wave_sum(s); s2 = wave_sum(s2);
  float mu = s * (1.0f/kC);
  float var = s2 * (1.0f/kC) - mu*mu;
  float rstd = rsqrtf(var + 1e-5f);
  #pragma unroll
  for (int i=0;i<5;i++){
    int c = lane + i*64;
    float o = (v[i]-mu)*rstd*g[c] + be[c];
    if (OB) ((unsigned short*)yv)[(size_t)row*kC + c] = f2b(o);
    else    ((float*)yv)[(size_t)row*kC + c] = o;
  }
}

// ---------------- merge ----------------
__global__ void k_merge_unm(const float* __restrict__ y, const int* __restrict__ a_idx,
                            const int* __restrict__ unm_list, float* __restrict__ xm){
  int blk = blockIdx.x; int b = blk >> 10; int s = blk & 1023;
  int i = unm_list[(size_t)b*kNB + s];
  int t = a_idx[i];
  const float* sp = y + ((size_t)b*kN + t)*kC;
  float* dp = xm + ((size_t)b*kNM + s)*kC;
  int lane = threadIdx.x;
  #pragma unroll
  for (int q=0;q<5;q++) dp[lane+q*64] = sp[lane+q*64];
}
__global__ void k_merge_dst(const float* __restrict__ y, float* __restrict__ xm, float* __restrict__ cnt){
  int blk = blockIdx.x; int b = blk >> 10; int j = blk & 1023;
  int t = 128*(j>>5) + 2*(j&31);
  const float* sp = y + ((size_t)b*kN + t)*kC;
  float* dp = xm + ((size_t)b*kNM + kNB + j)*kC;
  int lane = threadIdx.x;
  #pragma unroll
  for (int q=0;q<5;q++) dp[lane+q*64] = sp[lane+q*64];
  if (lane==0) cnt[(size_t)b*kNB + j] = 1.0f;
}
__global__ void k_merge_src(const float* __restrict__ y, const int* __restrict__ a_idx,
                            const int* __restrict__ merged, const int* __restrict__ node_idx,
                            float* __restrict__ xm, float* __restrict__ cnt){
  int blk = blockIdx.x; int b = blk / kNA; int i = blk % kNA;
  if (!merged[(size_t)b*kNA + i]) return;
  int t = a_idx[i]; int j = node_idx[(size_t)b*kNA + i];
  const float* sp = y + ((size_t)b*kN + t)*kC;
  float* dp = xm + ((size_t)b*kNM + kNB + j)*kC;
  int lane = threadIdx.x;
  #pragma unroll
  for (int q=0;q<5;q++) atomicAdd(&dp[lane+q*64], sp[lane+q*64]);
  if (lane==0) atomicAdd(&cnt[(size_t)b*kNB + j], 1.0f);
}
__global__ void k_merge_scale(float* __restrict__ xm, const float* __restrict__ cnt){
  int blk = blockIdx.x; int b = blk >> 10; int j = blk & 1023;
  float inv = 1.0f / cnt[(size_t)b*kNB + j];
  float* dp = xm + ((size_t)b*kNM + kNB + j)*kC;
  int lane = threadIdx.x;
  #pragma unroll
  for (int q=0;q<5;q++) dp[lane+q*64] *= inv;
}

// ---------------- weight transpose + bf16 convert: W[K x N] -> Wt[N x K] ----------------
__global__ __launch_bounds__(256) void k_wt(const float* __restrict__ W, unsigned short* __restrict__ Wt,
                                            int K, int N){
  __shared__ float tile[64][65];
  int k0 = blockIdx.x*64, n0 = blockIdx.y*64;
  int tid = threadIdx.x;
  #pragma unroll
  for (int l=0;l<16;l++){
    int e = tid + l*256; int r = e>>6, c = e&63;
    int gk = k0+r, gn = n0+c;
    tile[r][c] = (gk<K && gn<N) ? W[(size_t)gk*N+gn] : 0.f;
  }
  __syncthreads();
  #pragma unroll
  for (int l=0;l<16;l++){
    int e = tid + l*256; int r = e>>6, c = e&63;
    int gn = n0+r, gk = k0+c;
    if (gn<N && gk<K) Wt[(size_t)gn*K+gk] = f2b(tile[c][r]);
  }
}
__global__ void k_f2b(const float* __restrict__ x, unsigned short* __restrict__ y, int n){
  int i = blockIdx.x*256 + threadIdx.x;
  if (i<n) y[i] = f2b(x[i]);
}

// ---------------- bf16 MFMA GEMM: out[MxN] = A[MxK] @ Bt[NxK]^T (+bias)(+resid) ----------------
template<typename OT, bool BIAS, bool RES>
__global__ __launch_bounds__(256) void k_bgemm(const unsigned short* __restrict__ A,
    const unsigned short* __restrict__ Bt, const float* __restrict__ bias,
    const float* __restrict__ resid, OT* __restrict__ out, int M, int N, int K){
  constexpr int LDK = 72;
  __shared__ unsigned short As[128*LDK];
  __shared__ unsigned short Bs[128*LDK];
  const int tid = threadIdx.x;
  const int m0 = blockIdx.x*128, n0 = blockIdx.y*128;
  const int wid = tid>>6, lane = tid&63;
  const int wm = (wid>>1)*64, wn = (wid&1)*64;
  const int lr = lane&15, quad = lane>>4;
  const f32x4 zero4 = {0.f,0.f,0.f,0.f};
  f32x4 acc[4][4];
  #pragma unroll
  for (int i=0;i<4;i++)
    #pragma unroll
    for (int j=0;j<4;j++) acc[i][j] = zero4;
  for (int k0=0; k0<K; k0+=64){
    __syncthreads();
    #pragma unroll
    for (int l=0;l<4;l++){
      int e = tid + l*256;
      int row = e>>3, seg = (e&7)*8;
      int gm = m0+row;
      uint4 va = (gm<M) ? *reinterpret_cast<const uint4*>(&A[(size_t)gm*K + k0 + seg])
                        : make_uint4(0u,0u,0u,0u);
      *reinterpret_cast<uint4*>(&As[row*LDK + seg]) = va;
      int gn = n0+row;
      uint4 vb = (gn<N) ? *reinterpret_cast<const uint4*>(&Bt[(size_t)gn*K + k0 + seg])
                        : make_uint4(0u,0u,0u,0u);
      *reinterpret_cast<uint4*>(&Bs[row*LDK + seg]) = vb;
    }
    __syncthreads();
    #pragma unroll
    for (int kk=0; kk<64; kk+=32){
      bf16x8 af[4], bfr[4];
      #pragma unroll
      for (int i=0;i<4;i++) af[i]  = *reinterpret_cast<const bf16x8*>(&As[(wm+i*16+lr)*LDK + kk + quad*8]);
      #pragma unroll
      for (int j=0;j<4;j++) bfr[j] = *reinterpret_cast<const bf16x8*>(&Bs[(wn+j*16+lr)*LDK + kk + quad*8]);
      #pragma unroll
      for (int i=0;i<4;i++)
        #pragma unroll
        for (int j=0;j<4;j++)
          acc[i][j] = __builtin_amdgcn_mfma_f32_16x16x32_bf16(af[i], bfr[j], acc[i][j], 0, 0, 0);
    }
  }
  #pragma unroll
  for (int i=0;i<4;i++){
    #pragma unroll
    for (int j=0;j<4;j++){
      int gn = n0 + wn + j*16 + lr;
      if (gn >= N) continue;
      float bv = BIAS ? bias[gn] : 0.f;
      #pragma unroll
      for (int r=0;r<4;r++){
        int gm = m0 + wm + i*16 + quad*4 + r;
        if (gm >= M) continue;
        float v = acc[i][j][r] + bv;
        if (RES) v += resid[(size_t)gm*N + gn];
        if constexpr (sizeof(OT)==2) out[(size_t)gm*N + gn] = (OT)f2b(v);
        else                         out[(size_t)gm*N + gn] = (OT)v;
      }
    }
  }
}

// ---------------- GEGLU elementwise: G = H[:, :1280] * gelu(H[:, 1280:]) ----------------
__global__ void k_geglu(const unsigned short* __restrict__ H, unsigned short* __restrict__ G){
  int e = blockIdx.x*256 + threadIdx.x;   // 8192*160 threads
  int m = e/160, t = e - m*160;
  const unsigned short* hp = H + (size_t)m*2560 + t*8;
  uint4 xv = *reinterpret_cast<const uint4*>(hp);
  uint4 gv = *reinterpret_cast<const uint4*>(hp + 1280);
  const unsigned short* xu = reinterpret_cast<const unsigned short*>(&xv);
  const unsigned short* gu = reinterpret_cast<const unsigned short*>(&gv);
  unsigned short ov[8];
  #pragma unroll
  for (int d=0; d<8; d++){
    float x = b2f(xu[d]);
    float g = b2f(gu[d]);
    float ge = 0.5f*g*(1.0f + erff(g*0.70710678118654752f));
    ov[d] = f2b(x*ge);
  }
  *reinterpret_cast<uint4*>(G + (size_t)m*1280 + t*8) = *reinterpret_cast<const uint4*>(ov);
}

// ---------------- MFMA flash self-attn ----------------
// 64 queries/block, one head. QKV row stride 960 (Q|K|V). bf16 MFMA for S=QK^T and O+=PV.
// K row-major IS the B operand layout; only V transposed (during staging).
// S/O fragments share row map (m=quad*4+reg) -> softmax state fully in registers.
__global__ __launch_bounds__(256) void k_attn1(const unsigned short* __restrict__ QKV,
                                               unsigned short* __restrict__ Oa){
  constexpr int LP = 72;
  __shared__ unsigned short Qs[64*LP];
  __shared__ unsigned short Ks[64*LP];
  __shared__ unsigned short Vt[48*LP];
  __shared__ unsigned short Ps[64*LP];
  const int b = blockIdx.z, hh = blockIdx.y;
  const int q0 = blockIdx.x*64;
  const int tid = threadIdx.x;
  const int wid = tid>>6, lane = tid&63;
  const int lr = lane&15, quad = lane>>4;
  const int wm = wid*16;
  const float scale = 0.15811388300841898f; // 1/sqrt(40)
  const unsigned short* Qb = QKV + ((size_t)b*kNM + q0)*960 + hh*kDH;
  const unsigned short* Kb = QKV + ((size_t)b*kNM)*960 + 320 + hh*kDH;
  const unsigned short* Vb = QKV + ((size_t)b*kNM)*960 + 640 + hh*kDH;
  const uint4 z4 = make_uint4(0u,0u,0u,0u);
  // zero K-dim pads (cols 40..63 of Qs/Ks; rows 40..47 of Vt) once
  for (int e=tid; e<192; e+=256){
    int row=e/3, seg=40+(e%3)*8;
    *reinterpret_cast<uint4*>(&Qs[row*LP+seg]) = z4;
    *reinterpret_cast<uint4*>(&Ks[row*LP+seg]) = z4;
  }
  for (int e=tid; e<72; e+=256){
    int row=40+e/9, seg=(e%9)*8;
    *reinterpret_cast<uint4*>(&Vt[row*LP+seg]) = z4;
  }
  // stage Q once (row-major = A operand layout)
  for (int e=tid; e<320; e+=256){
    int row=e/5, seg=(e%5)*8;
    *reinterpret_cast<uint4*>(&Qs[row*LP+seg]) =
      *reinterpret_cast<const uint4*>(Qb + (size_t)row*960 + seg);
  }
  const f32x4 zf = {0.f,0.f,0.f,0.f};
  f32x4 oacc[3] = {zf, zf, zf};
  float m_i[4], l_i[4];
  #pragma unroll
  for (int r=0;r<4;r++){ m_i[r] = -1e30f; l_i[r] = 0.f; }
  for (int kt=0; kt<kNM; kt+=64){
    __syncthreads();   // prev tile's Ks/Vt reads done
    for (int e=tid; e<320; e+=256){
      int row=e/5, seg=(e%5)*8;
      *reinterpret_cast<uint4*>(&Ks[row*LP+seg]) =
        *reinterpret_cast<const uint4*>(Kb + (size_t)(kt+row)*960 + seg);
      uint4 v = *reinterpret_cast<const uint4*>(Vb + (size_t)(kt+row)*960 + seg);
      const unsigned short* u = reinterpret_cast<const unsigned short*>(&v);
      #pragma unroll
      for (int d=0; d<8; d++) Vt[(seg+d)*LP + row] = u[d];
    }
    __syncthreads();
    // S = Q.K^T  (K-dim = 64 padded head dims, 2 mfma steps)
    f32x4 sacc[4] = {zf, zf, zf, zf};
    bf16x8 aq0 = *reinterpret_cast<const bf16x8*>(&Qs[(wm+lr)*LP + quad*8]);
    bf16x8 aq1 = *reinterpret_cast<const bf16x8*>(&Qs[(wm+lr)*LP + 32 + quad*8]);
    #pragma unroll
    for (int j=0;j<4;j++){
      bf16x8 bk0 = *reinterpret_cast<const bf16x8*>(&Ks[(j*16+lr)*LP + quad*8]);
      sacc[j] = __builtin_amdgcn_mfma_f32_16x16x32_bf16(aq0, bk0, sacc[j], 0,0,0);
      bf16x8 bk1 = *reinterpret_cast<const bf16x8*>(&Ks[(j*16+lr)*LP + 32 + quad*8]);
      sacc[j] = __builtin_amdgcn_mfma_f32_16x16x32_bf16(aq1, bk1, sacc[j], 0,0,0);
    }
    // online softmax per row (m = wm + quad*4 + r); P -> LDS bf16 (A-operand layout)
    #pragma unroll
    for (int r=0;r<4;r++){
      float v0=sacc[0][r]*scale, v1=sacc[1][r]*scale, v2=sacc[2][r]*scale, v3=sacc[3][r]*scale;
      float rm = fmaxf(fmaxf(v0,v1), fmaxf(v2,v3));
      #pragma unroll
      for (int off=1; off<16; off<<=1) rm = fmaxf(rm, __shfl_xor(rm, off, 64));
      float mnew = fmaxf(m_i[r], rm);
      float alpha = __expf(m_i[r] - mnew);
      float p0=__expf(v0-mnew), p1=__expf(v1-mnew), p2=__expf(v2-mnew), p3=__expf(v3-mnew);
      float psum = p0+p1+p2+p3;
      #pragma unroll
      for (int off=1; off<16; off<<=1) psum += __shfl_xor(psum, off, 64);
      l_i[r] = l_i[r]*alpha + psum;
      m_i[r] = mnew;
      int row = wm + quad*4 + r;
      Ps[row*LP +      lr] = f2b(p0);
      Ps[row*LP + 16 + lr] = f2b(p1);
      Ps[row*LP + 32 + lr] = f2b(p2);
      Ps[row*LP + 48 + lr] = f2b(p3);
      oacc[0][r] *= alpha; oacc[1][r] *= alpha; oacc[2][r] *= alpha;
    }
    // O += P.V  (Ps rows written & read by this wave only -> no barrier)
    #pragma unroll
    for (int s=0;s<2;s++){
      bf16x8 ap = *reinterpret_cast<const bf16x8*>(&Ps[(wm+lr)*LP + s*32 + quad*8]);
      #pragma unroll
      for (int nt=0;nt<3;nt++){
        bf16x8 bv = *reinterpret_cast<const bf16x8*>(&Vt[(nt*16+lr)*LP + s*32 + quad*8]);
        oacc[nt] = __builtin_amdgcn_mfma_f32_16x16x32_bf16(ap, bv, oacc[nt], 0,0,0);
      }
    }
  }
  // epilogue: O[m][d], m = wm+quad*4+r, d = nt*16+lr (d<40)
  #pragma unroll
  for (int r=0;r<4;r++){
    float inv = 1.0f / l_i[r];
    unsigned short* Ob = Oa + ((size_t)b*kNM + q0 + wm + quad*4 + r)*kC + hh*kDH;
    #pragma unroll
    for (int nt=0;nt<3;nt++){
      int d = nt*16 + lr;
      if (d < kDH) Ob[d] = f2b(oacc[nt][r]*inv);
    }
  }
}

// cross-attn: bf16 I/O. KV row stride 640 (K|V fused).
__global__ __launch_bounds__(1024) void k_attn2(const unsigned short* __restrict__ Q,
                                                const unsigned short* __restrict__ KV,
                                                unsigned short* __restrict__ Oa){
  __shared__ float Ks[kLC][41];
  __shared__ float Vs[kLC][41];
  __shared__ float qs[16][41];
  __shared__ float ps[16][80];
  const int b = blockIdx.z, hh = blockIdx.y;
  const int tid = threadIdx.x, wv = tid>>6, lane = tid&63;
  const int hoff = hh*kDH;
  for (int e=tid; e<kLC*kDH; e+=1024){
    int kk = e/kDH, d = e - kk*kDH;
    size_t off = ((size_t)b*kLC + kk)*640 + hoff + d;
    Ks[kk][d] = b2f(KV[off]);
    Vs[kk][d] = b2f(KV[off + 320]);
  }
  const int q = blockIdx.x*16 + wv;
  if (lane < kDH) qs[wv][lane] = b2f(Q[((size_t)b*kN + q)*kC + hoff + lane]);
  __syncthreads();
  const bool has2 = (lane + 64) < kLC;
  const int k2i = has2 ? lane+64 : 0;
  float s0=0.f, s1=0.f;
  #pragma unroll
  for (int d=0; d<kDH; d++){
    float qd = qs[wv][d];
    s0 = fmaf(qd, Ks[lane][d], s0);
    s1 = fmaf(qd, Ks[k2i][d], s1);
  }
  s0 *= 0.15811388300841898f;
  s1 = has2 ? s1*0.15811388300841898f : -1e30f;
  float mx = wave_max(fmaxf(s0, s1));
  float p0 = __expf(s0-mx);
  float p1 = has2 ? __expf(s1-mx) : 0.f;
  ps[wv][lane] = p0;
  if (has2) ps[wv][64+lane] = p1;
  float l = wave_sum(p0+p1);
  if (lane < kDH){
    float acc = 0.f;
    #pragma unroll
    for (int k3=0;k3<kLC;k3++) acc = fmaf(ps[wv][k3], Vs[k3][lane], acc);
    Oa[((size_t)b*kN + q)*kC + hoff + lane] = f2b(acc / l);
  }
}

// ---------------- unmerge + residual ----------------
__global__ void k_unmerge(const float* __restrict__ net, const float* __restrict__ Xo,
                          const int* __restrict__ merged, const int* __restrict__ node_idx,
                          const int* __restrict__ slot_of, float* __restrict__ net1){
  int blk = blockIdx.x; int b = blk >> 12; int t = blk & 4095;
  int h = t>>6, w = t&63;
  int row;
  if (!((h|w)&1)) row = kNB + ((h>>1)*32 + (w>>1));
  else {
    int i = d_arank(h,w);
    row = merged[(size_t)b*kNA+i] ? (kNB + node_idx[(size_t)b*kNA+i]) : slot_of[(size_t)b*kNA+i];
  }
  const float* np_ = net + ((size_t)b*kN + t)*kC;
  const float* xp = Xo + ((size_t)b*kNM + row)*kC;
  float* op = net1 + ((size_t)b*kN + t)*kC;
  int lane = threadIdx.x;
  #pragma unroll
  for (int q=0;q<5;q++){ int c = lane+q*64; op[c] = np_[c] + xp[c]; }
}

// ---------------- launch ----------------
extern "C" void kernel_launch(void* const* d_in, const int* in_sizes, int n_in,
                              void* d_out, int out_size, void* d_ws, size_t ws_size,
                              hipStream_t stream){
  const float* net = (const float*)d_in[0];
  const float* ctx = (const float*)d_in[1];
  const float* ln1g=(const float*)d_in[2], *ln1b=(const float*)d_in[3];
  const float* ln2g=(const float*)d_in[4], *ln2b=(const float*)d_in[5];
  const float* ln3g=(const float*)d_in[6], *ln3b=(const float*)d_in[7];
  const float* w1q=(const float*)d_in[8],  *w1k=(const float*)d_in[9];
  const float* w1v=(const float*)d_in[10], *w1o=(const float*)d_in[11];
  const float* b1o=(const float*)d_in[12];
  const float* w2q=(const float*)d_in[13], *w2k=(const float*)d_in[14];
  const float* w2v=(const float*)d_in[15], *w2o=(const float*)d_in[16];
  const float* b2o=(const float*)d_in[17];
  const float* fw1=(const float*)d_in[18], *fb1=(const float*)d_in[19];
  const float* fw2=(const float*)d_in[20], *fb2=(const float*)d_in[21];

  char* ws = (char*)d_ws;
  float* mnA  = (float*)(ws + B_mnA);
  float* mnB  = (float*)(ws + B_mnB);
  float* y32  = (float*)(ws + B_y32);
  float* xm32 = (float*)(ws + B_xm);
  float* Xo1  = (float*)(ws + B_xo1);
  float* net1 = (float*)(ws + B_net1);
  float* net2 = (float*)(ws + B_net2);
  float* cnt  = (float*)(ws + B_cnt);
  unsigned short* Hb   = (unsigned short*)(ws + B_H);
  unsigned short* Gb   = (unsigned short*)(ws + B_G);
  unsigned short* QKVb = (unsigned short*)(ws + B_QKVb);
  unsigned short* yb   = (unsigned short*)(ws + B_yb);
  unsigned short* xmb  = (unsigned short*)(ws + B_xmb);
  unsigned short* Ao1b = (unsigned short*)(ws + B_Ao1b);
  unsigned short* Q2b  = (unsigned short*)(ws + B_Q2b);
  unsigned short* Ao2b = (unsigned short*)(ws + B_Ao2b);
  unsigned short* KV2b = (unsigned short*)(ws + B_KV2b);
  unsigned short* ctxb = (unsigned short*)(ws + B_ctxb);
  unsigned short* Wqkv = (unsigned short*)(ws + B_Wqkv);
  unsigned short* Wo1  = (unsigned short*)(ws + B_Wo1);
  unsigned short* Wq2  = (unsigned short*)(ws + B_Wq2);
  unsigned short* Wkv2 = (unsigned short*)(ws + B_Wkv2);
  unsigned short* Wo2  = (unsigned short*)(ws + B_Wo2);
  unsigned short* Wff1 = (unsigned short*)(ws + B_Wff1);
  unsigned short* Wff2 = (unsigned short*)(ws + B_Wff2);
  unsigned long long* pack = (unsigned long long*)(ws + B_pack);
  unsigned int* nmkey = (unsigned int*)(ws + B_key);
  int* nidx = (int*)(ws + B_nidx); int* mrg = (int*)(ws + B_mrg); int* slot = (int*)(ws + B_slot);
  int* unml = (int*)(ws + B_unml); int* ucnt = (int*)(ws + B_ucnt); int* aidx = (int*)(ws + B_aidx);

  // --- weight conversion (transpose to [N x K] bf16) ---
  k_wt<<<dim3(5,5),   256, 0, stream>>>(w1q, Wqkv,             320, 320);
  k_wt<<<dim3(5,5),   256, 0, stream>>>(w1k, Wqkv + 320*320,   320, 320);
  k_wt<<<dim3(5,5),   256, 0, stream>>>(w1v, Wqkv + 640*320,   320, 320);
  k_wt<<<dim3(5,5),   256, 0, stream>>>(w1o, Wo1,              320, 320);
  k_wt<<<dim3(5,5),   256, 0, stream>>>(w2q, Wq2,              320, 320);
  k_wt<<<dim3(12,5),  256, 0, stream>>>(w2k, Wkv2,             768, 320);
  k_wt<<<dim3(12,5),  256, 0, stream>>>(w2v, Wkv2 + 320*768,   768, 320);
  k_wt<<<dim3(5,5),   256, 0, stream>>>(w2o, Wo2,              320, 320);
  k_wt<<<dim3(5,40),  256, 0, stream>>>(fw1, Wff1,             320, 2560);
  k_wt<<<dim3(20,5),  256, 0, stream>>>(fw2, Wff2,             1280, 320);
  k_f2b<<<(kB*kLC*kDC+255)/256, 256, 0, stream>>>(ctx, ctxb, kB*kLC*kDC);

  // --- ToMe indices (exact fp32) ---
  k_idx   <<<16, 256, 0, stream>>>(aidx);
  k_init  <<<(kB*kNA+255)/256, 256, 0, stream>>>(pack, ucnt);
  k_gather<<<kB*kN, 64, 0, stream>>>(net, mnA, mnB);
  k_scores<<<dim3(kNA/64, kNB/64, kB), 256, 0, stream>>>(mnA, mnB, pack);
  k_decode<<<(kB*kNA+255)/256, 256, 0, stream>>>(pack, nmkey, nidx);
  k_rank  <<<dim3(kNA/256, kB), 256, 0, stream>>>(nmkey, mrg, slot, unml, ucnt);
  // --- merge(LN1(net)) ---
  k_ln<false><<<kB*kN, 64, 0, stream>>>(net, ln1g, ln1b, y32);
  k_merge_unm  <<<kB*kNB, 64, 0, stream>>>(y32, aidx, unml, xm32);
  k_merge_dst  <<<kB*kNB, 64, 0, stream>>>(y32, xm32, cnt);
  k_merge_src  <<<kB*kNA, 64, 0, stream>>>(y32, aidx, mrg, nidx, xm32, cnt);
  k_merge_scale<<<kB*kNB, 64, 0, stream>>>(xm32, cnt);
  k_f2b<<<(kB*kNM*kC+255)/256, 256, 0, stream>>>(xm32, xmb, kB*kNM*kC);
  // --- attn1 (self, merged seq) ---
  k_bgemm<unsigned short,false,false><<<dim3(32,8), 256, 0, stream>>>(xmb, Wqkv, nullptr, nullptr, QKVb, 4096, 960, 320);
  k_attn1<<<dim3(kNM/64, kH, kB), 256, 0, stream>>>(QKVb, Ao1b);
  k_bgemm<float,true,false><<<dim3(32,3), 256, 0, stream>>>(Ao1b, Wo1, b1o, nullptr, Xo1, 4096, 320, 320);
  k_unmerge<<<kB*kN, 64, 0, stream>>>(net, Xo1, mrg, nidx, slot, net1);
  // --- attn2 (cross) ---
  k_ln<true><<<kB*kN, 64, 0, stream>>>(net1, ln2g, ln2b, yb);
  k_bgemm<unsigned short,false,false><<<dim3(64,3), 256, 0, stream>>>(yb, Wq2, nullptr, nullptr, Q2b, 8192, 320, 320);
  k_bgemm<unsigned short,false,false><<<dim3(2,5), 256, 0, stream>>>(ctxb, Wkv2, nullptr, nullptr, KV2b, 154, 640, 768);
  k_attn2<<<dim3(kN/16, kH, kB), 1024, 0, stream>>>(Q2b, KV2b, Ao2b);
  k_bgemm<float,true,true><<<dim3(64,3), 256, 0, stream>>>(Ao2b, Wo2, b2o, net1, net2, 8192, 320, 320);
  // --- GEGLU FF ---
  k_ln<true><<<kB*kN, 64, 0, stream>>>(net2, ln3g, ln3b, yb);
  k_bgemm<unsigned short,true,false><<<dim3(64,20), 256, 0, stream>>>(yb, Wff1, fb1, nullptr, Hb, 8192, 2560, 320);
  k_geglu<<<(kB*kN*160+255)/256, 256, 0, stream>>>(Hb, Gb);
  k_bgemm<float,true,true><<<dim3(64,3), 256, 0, stream>>>(Gb, Wff2, fb2, net2, (float*)d_out, 8192, 320, 1280);
}

// Round 7
// 646.531 us; speedup vs baseline: 2.7117x; 1.1742x over previous
//
#include <hip/hip_runtime.h>

typedef __attribute__((ext_vector_type(8))) short bf16x8;
typedef __attribute__((ext_vector_type(4))) float f32x4;

// ---------------- problem constants ----------------
constexpr int kB   = 2;
constexpr int kN   = 4096;   // tokens (64x64)
constexpr int kC   = 320;    // channels
constexpr int kNA  = 3072;   // src (non-dst) tokens
constexpr int kNB  = 1024;   // dst tokens
constexpr int kNM  = 2048;   // merged seq len
constexpr int kR   = 2048;   // merged src count
constexpr int kH   = 8;
constexpr int kDH  = 40;
constexpr int kLC  = 77;
constexpr int kDC  = 768;
constexpr int kDFF = 1280;

__device__ __forceinline__ unsigned short f2b(float f){
  unsigned u = __float_as_uint(f);
  u += 0x7FFF + ((u>>16)&1);
  return (unsigned short)(u>>16);
}
__device__ __forceinline__ float b2f(unsigned short h){ return __uint_as_float(((unsigned)h)<<16); }

__device__ __forceinline__ float wave_sum(float v){
  #pragma unroll
  for (int m=32;m>=1;m>>=1) v += __shfl_xor(v, m, 64);
  return v;
}
__device__ __forceinline__ int d_arank(int h, int w){
  int base = 32*((h+1)>>1) + 64*(h>>1);
  return base + ((h&1) ? w : (w>>1));
}

// ---------------- ws layout (byte offsets) ----------------
constexpr size_t rndB(size_t x){ return (x + 255) & ~(size_t)255; }
constexpr size_t B_mnA  = 0;                                             // fp32 [2*3072*320]
constexpr size_t B_mnB  = rndB(B_mnA + (size_t)kB*kNA*kC*4);             // fp32 [2*1024*320]
constexpr size_t B_y32  = rndB(B_mnB + (size_t)kB*kNB*kC*4);             // fp32 [2*4096*320] (LN1)
constexpr size_t B_xm   = rndB(B_y32 + (size_t)kB*kN*kC*4);              // fp32 [2*2048*320]
constexpr size_t B_xo1  = rndB(B_xm  + (size_t)kB*kNM*kC*4);             // fp32 [2*2048*320]
constexpr size_t B_net1 = rndB(B_xo1 + (size_t)kB*kNM*kC*4);             // fp32 [2*4096*320]
constexpr size_t B_H    = 0;  // bf16 [8192*2560] overlays mnA..net1 (41.94 MB, all dead by then)
constexpr size_t B_net2 = rndB(B_net1 + (size_t)kB*kN*kC*4);             // fp32 [2*4096*320]
constexpr size_t B_G    = rndB(B_net2 + (size_t)kB*kN*kC*4);             // bf16 [8192*1280]
constexpr size_t B_QKb  = rndB(B_G    + (size_t)kB*kN*kDFF*2);           // bf16 [4096*640] (Q|K)
constexpr size_t B_Vtg  = rndB(B_QKb  + (size_t)kB*kNM*640*2);           // bf16 [320*4096] (V^T)
constexpr size_t B_yb   = rndB(B_Vtg  + (size_t)320*kB*kNM*2);           // bf16 [8192*320]
constexpr size_t B_xmb  = rndB(B_yb   + (size_t)kB*kN*kC*2);             // bf16 [4096*320]
constexpr size_t B_Ao1b = rndB(B_xmb  + (size_t)kB*kNM*kC*2);            // bf16 [4096*320]
constexpr size_t B_Q2b  = rndB(B_Ao1b + (size_t)kB*kNM*kC*2);            // bf16 [8192*320]
constexpr size_t B_Ao2b = rndB(B_Q2b  + (size_t)kB*kN*kC*2);             // bf16 [8192*320]
constexpr size_t B_KV2b = rndB(B_Ao2b + (size_t)kB*kN*kC*2);             // bf16 [154*640]
constexpr size_t B_Vt2g = rndB(B_KV2b + (size_t)kB*kLC*640*2);           // bf16 [2*320*80] (V2^T pad)
constexpr size_t B_ctxb = rndB(B_Vt2g + (size_t)kB*320*80*2);            // bf16 [154*768]
constexpr size_t B_Wqkv = rndB(B_ctxb + (size_t)kB*kLC*kDC*2);           // bf16 [960*320]
constexpr size_t B_Wo1  = rndB(B_Wqkv + (size_t)960*320*2);              // bf16 [320*320]
constexpr size_t B_Wq2  = rndB(B_Wo1  + (size_t)320*320*2);
constexpr size_t B_Wkv2 = rndB(B_Wq2  + (size_t)320*320*2);              // bf16 [640*768]
constexpr size_t B_Wo2  = rndB(B_Wkv2 + (size_t)640*768*2);
constexpr size_t B_Wff1 = rndB(B_Wo2  + (size_t)320*320*2);              // bf16 [2560*320]
constexpr size_t B_Wff2 = rndB(B_Wff1 + (size_t)2560*320*2);             // bf16 [320*1280]
constexpr size_t B_cnt  = rndB(B_Wff2 + (size_t)320*1280*2);             // fp32 [2*1024]
constexpr size_t B_pack = rndB(B_cnt  + (size_t)kB*kNB*4);               // u64 [2*3072]
constexpr size_t B_key  = rndB(B_pack + (size_t)kB*kNA*8);
constexpr size_t B_nidx = rndB(B_key  + (size_t)kB*kNA*4);
constexpr size_t B_mrg  = rndB(B_nidx + (size_t)kB*kNA*4);
constexpr size_t B_slot = rndB(B_mrg  + (size_t)kB*kNA*4);
constexpr size_t B_unml = rndB(B_slot + (size_t)kB*kNA*4);
constexpr size_t B_ucnt = rndB(B_unml + (size_t)kB*kNB*4);
constexpr size_t B_aidx = rndB(B_ucnt + 64);

// ---------------- small setup kernels ----------------
__global__ void k_idx(int* __restrict__ a_idx){
  int t = blockIdx.x*256 + threadIdx.x;
  if (t >= kN) return;
  int h = t>>6, w = t&63;
  if ((h|w)&1) a_idx[d_arank(h,w)] = t;
}
__global__ void k_init(unsigned long long* __restrict__ pack, int* __restrict__ ucnt){
  int i = blockIdx.x*256 + threadIdx.x;
  if (i < kB*kNA) pack[i] = 0ull;
  if (i < kB) ucnt[i] = 0;
}
__global__ void k_gather(const float* __restrict__ net, float* __restrict__ mA, float* __restrict__ mB){
  int blk = blockIdx.x; int b = blk >> 12; int t = blk & 4095;
  int lane = threadIdx.x;
  const float* xp = net + ((size_t)b*kN + t)*kC;
  float v[5]; float s2 = 0.f;
  #pragma unroll
  for (int i=0;i<5;i++){ float f = xp[lane + i*64]; v[i]=f; s2 += f*f; }
  s2 = wave_sum(s2);
  float rn = 1.0f / sqrtf(s2);
  int h=t>>6, w=t&63;
  float* dp;
  if (!((h|w)&1)) dp = mB + ((size_t)b*kNB + ((h>>1)*32+(w>>1)))*kC;
  else            dp = mA + ((size_t)b*kNA + d_arank(h,w))*kC;
  #pragma unroll
  for (int i=0;i<5;i++) dp[lane + i*64] = v[i]*rn;
}

// ---------------- fused score GEMM (NT, exact fp32) + row argmax ----------------
__global__ __launch_bounds__(256) void k_scores(const float* __restrict__ mA, const float* __restrict__ mB,
                                                unsigned long long* __restrict__ pack){
  __shared__ __align__(16) float As[16][68];
  __shared__ __align__(16) float Bs[16][68];
  const int b = blockIdx.z;
  const int m0 = blockIdx.x*64, n0 = blockIdx.y*64;
  const int tid = threadIdx.x;
  const int mr = tid>>4, nc = tid&15;
  const int lr = tid>>2, lc4 = (tid&3)*4;
  const float* Ab = mA + (size_t)b*kNA*kC;
  const float* Bb = mB + (size_t)b*kNB*kC;
  float acc[4][4] = {};
  for (int k0=0; k0<kC; k0+=16){
    __syncthreads();
    {
      float4 av = *reinterpret_cast<const float4*>(&Ab[(size_t)(m0+lr)*kC + k0 + lc4]);
      As[lc4+0][lr]=av.x; As[lc4+1][lr]=av.y; As[lc4+2][lr]=av.z; As[lc4+3][lr]=av.w;
      float4 bv = *reinterpret_cast<const float4*>(&Bb[(size_t)(n0+lr)*kC + k0 + lc4]);
      Bs[lc4+0][lr]=bv.x; Bs[lc4+1][lr]=bv.y; Bs[lc4+2][lr]=bv.z; Bs[lc4+3][lr]=bv.w;
    }
    __syncthreads();
    #pragma unroll
    for (int kk=0;kk<16;kk++){
      const float4 a4 = *reinterpret_cast<const float4*>(&As[kk][mr*4]);
      const float4 b4 = *reinterpret_cast<const float4*>(&Bs[kk][nc*4]);
      const float aa[4]={a4.x,a4.y,a4.z,a4.w};
      const float bb[4]={b4.x,b4.y,b4.z,b4.w};
      #pragma unroll
      for (int i=0;i<4;i++)
        #pragma unroll
        for (int j=0;j<4;j++)
          acc[i][j] = fmaf(aa[i], bb[j], acc[i][j]);
    }
  }
  #pragma unroll
  for (int i=0;i<4;i++){
    float bs = acc[i][0]; int bj = n0 + nc*4;
    #pragma unroll
    for (int j=1;j<4;j++){
      float v = acc[i][j];
      if (v > bs){ bs=v; bj=n0+nc*4+j; }
    }
    #pragma unroll
    for (int off=1; off<16; off<<=1){
      float os = __shfl_xor(bs, off, 16);
      int   oj = __shfl_xor(bj, off, 16);
      if (os > bs || (os == bs && oj < bj)){ bs=os; bj=oj; }
    }
    if (nc == 0){
      unsigned int u = __float_as_uint(bs);
      unsigned int key = (u & 0x80000000u) ? ~u : (u | 0x80000000u);
      unsigned long long pk = ((unsigned long long)key << 32) |
                              (unsigned long long)(0xFFFFFFFFu - (unsigned int)bj);
      atomicMax(&pack[(size_t)b*kNA + m0 + mr*4 + i], pk);
    }
  }
}
__global__ void k_decode(const unsigned long long* __restrict__ pack, unsigned int* __restrict__ nmkey,
                         int* __restrict__ node_idx){
  int i = blockIdx.x*256 + threadIdx.x;
  if (i >= kB*kNA) return;
  unsigned long long p = pack[i];
  nmkey[i]    = (unsigned int)(p>>32);
  node_idx[i] = (int)(0xFFFFFFFFu - (unsigned int)(p & 0xFFFFFFFFull));
}
__global__ __launch_bounds__(256) void k_rank(const unsigned int* __restrict__ nmkey, int* __restrict__ merged,
                                              int* __restrict__ slot_of, int* __restrict__ unm_list,
                                              int* __restrict__ ucnt){
  __shared__ unsigned int keys[kNA];
  int b = blockIdx.y;
  int i = blockIdx.x*256 + threadIdx.x;
  const unsigned int* kb = nmkey + (size_t)b*kNA;
  for (int idx=threadIdx.x; idx<kNA; idx+=256) keys[idx] = kb[idx];
  __syncthreads();
  unsigned int ki = keys[i];
  int rank = 0;
  for (int j=0;j<kNA;j++){
    unsigned int kj = keys[j];
    rank += (kj > ki) || (kj == ki && j < i);
  }
  int mg = rank < kR;
  merged[(size_t)b*kNA + i] = mg;
  if (!mg){
    int s = atomicAdd(&ucnt[b], 1);
    unm_list[(size_t)b*kNB + s] = i;
    slot_of[(size_t)b*kNA + i] = s;
  }
}

// ---------------- layernorm (OB: bf16 out) ----------------
template<bool OB>
__global__ void k_ln(const float* __restrict__ x, const float* __restrict__ g,
                     const float* __restrict__ be, void* __restrict__ yv){
  const int row = blockIdx.x;
  const int lane = threadIdx.x;
  const float* xp = x + (size_t)row*kC;
  float v[5]; float s=0.f, s2=0.f;
  #pragma unroll
  for (int i=0;i<5;i++){ float f = xp[lane + i*64]; v[i]=f; s+=f; s2+=f*f; }
  s = wave_sum(s); s2 = wave_sum(s2);
  float mu = s * (1.0f/kC);
  float var = s2 * (1.0f/kC) - mu*mu;
  float rstd = rsqrtf(var + 1e-5f);
  #pragma unroll
  for (int i=0;i<5;i++){
    int c = lane + i*64;
    float o = (v[i]-mu)*rstd*g[c] + be[c];
    if (OB) ((unsigned short*)yv)[(size_t)row*kC + c] = f2b(o);
    else    ((float*)yv)[(size_t)row*kC + c] = o;
  }
}

// ---------------- merge ----------------
__global__ void k_merge_unm(const float* __restrict__ y, const int* __restrict__ a_idx,
                            const int* __restrict__ unm_list, unsigned short* __restrict__ xmb){
  int blk = blockIdx.x; int b = blk >> 10; int s = blk & 1023;
  int i = unm_list[(size_t)b*kNB + s];
  int t = a_idx[i];
  const float* sp = y + ((size_t)b*kN + t)*kC;
  unsigned short* dp = xmb + ((size_t)b*kNM + s)*kC;
  int lane = threadIdx.x;
  #pragma unroll
  for (int q=0;q<5;q++) dp[lane+q*64] = f2b(sp[lane+q*64]);
}
__global__ void k_merge_dst(const float* __restrict__ y, float* __restrict__ xm, float* __restrict__ cnt){
  int blk = blockIdx.x; int b = blk >> 10; int j = blk & 1023;
  int t = 128*(j>>5) + 2*(j&31);
  const float* sp = y + ((size_t)b*kN + t)*kC;
  float* dp = xm + ((size_t)b*kNM + kNB + j)*kC;
  int lane = threadIdx.x;
  #pragma unroll
  for (int q=0;q<5;q++) dp[lane+q*64] = sp[lane+q*64];
  if (lane==0) cnt[(size_t)b*kNB + j] = 1.0f;
}
__global__ void k_merge_src(const float* __restrict__ y, const int* __restrict__ a_idx,
                            const int* __restrict__ merged, const int* __restrict__ node_idx,
                            float* __restrict__ xm, float* __restrict__ cnt){
  int blk = blockIdx.x; int b = blk / kNA; int i = blk % kNA;
  if (!merged[(size_t)b*kNA + i]) return;
  int t = a_idx[i]; int j = node_idx[(size_t)b*kNA + i];
  const float* sp = y + ((size_t)b*kN + t)*kC;
  float* dp = xm + ((size_t)b*kNM + kNB + j)*kC;
  int lane = threadIdx.x;
  #pragma unroll
  for (int q=0;q<5;q++) atomicAdd(&dp[lane+q*64], sp[lane+q*64]);
  if (lane==0) atomicAdd(&cnt[(size_t)b*kNB + j], 1.0f);
}
__global__ void k_merge_scale(const float* __restrict__ xm, const float* __restrict__ cnt,
                              unsigned short* __restrict__ xmb){
  int blk = blockIdx.x; int b = blk >> 10; int j = blk & 1023;
  float inv = 1.0f / cnt[(size_t)b*kNB + j];
  const float* sp = xm + ((size_t)b*kNM + kNB + j)*kC;
  unsigned short* dp = xmb + ((size_t)b*kNM + kNB + j)*kC;
  int lane = threadIdx.x;
  #pragma unroll
  for (int q=0;q<5;q++) dp[lane+q*64] = f2b(sp[lane+q*64]*inv);
}

// ---------------- batched weight transpose+convert + ctx convert ----------------
__global__ __launch_bounds__(256) void k_wt_all(
    const float* __restrict__ w0, const float* __restrict__ w1, const float* __restrict__ w2,
    const float* __restrict__ w3, const float* __restrict__ w4, const float* __restrict__ w5,
    const float* __restrict__ w6, const float* __restrict__ w7, const float* __restrict__ w8,
    const float* __restrict__ w9,
    unsigned short* __restrict__ Wqkv, unsigned short* __restrict__ Wo1,
    unsigned short* __restrict__ Wq2,  unsigned short* __restrict__ Wkv2,
    unsigned short* __restrict__ Wo2,  unsigned short* __restrict__ Wff1,
    unsigned short* __restrict__ Wff2,
    const float* __restrict__ ctx, unsigned short* __restrict__ ctxb){
  const int bid = blockIdx.x;
  const int tid = threadIdx.x;
  if (bid >= 570){
    int base = (bid-570)*2048 + tid*8;
    #pragma unroll
    for (int j=0;j<8;j++){
      int i = base + j;
      if (i < kB*kLC*kDC) ctxb[i] = f2b(ctx[i]);
    }
    return;
  }
  const int jb[11]   = {0,25,50,75,100,125,185,245,270,470,570};
  const float* srcs[10] = {w0,w1,w2,w3,w4,w5,w6,w7,w8,w9};
  unsigned short* dsts[10] = {Wqkv, Wqkv+320*320, Wqkv+640*320, Wo1, Wq2,
                              Wkv2, Wkv2+320*768, Wo2, Wff1, Wff2};
  const int Kd[10] = {320,320,320,320,320,768,768,320,320,1280};
  const int Nd[10] = {320,320,320,320,320,320,320,320,2560,320};
  int job = 0;
  while (bid >= jb[job+1]) job++;
  int local = bid - jb[job];
  const int Nt = (Nd[job]+63)>>6;
  int k0 = (local / Nt)*64, n0 = (local % Nt)*64;
  const float* W = srcs[job];
  unsigned short* Wt = dsts[job];
  const int K = Kd[job], N = Nd[job];
  __shared__ float tile[64][65];
  #pragma unroll
  for (int l=0;l<16;l++){
    int e = tid + l*256; int r = e>>6, c = e&63;
    int gk = k0+r, gn = n0+c;
    tile[r][c] = (gk<K && gn<N) ? W[(size_t)gk*N+gn] : 0.f;
  }
  __syncthreads();
  #pragma unroll
  for (int l=0;l<16;l++){
    int e = tid + l*256; int r = e>>6, c = e&63;
    int gn = n0+r, gk = k0+c;
    if (gn<N && gk<K) Wt[(size_t)gn*K+gk] = f2b(tile[c][r]);
  }
}

// ---------------- bf16 MFMA GEMM: out[MxN] = A[MxK] @ Bt[NxK]^T (+bias)(+resid) ----------------
// SV: columns >= 640 are written transposed to vt[(gn-640)*4096 + gm]; out stride = ldo.
template<typename OT, bool BIAS, bool RES, bool SV>
__global__ __launch_bounds__(256) void k_bgemm(const unsigned short* __restrict__ A,
    const unsigned short* __restrict__ Bt, const float* __restrict__ bias,
    const float* __restrict__ resid, OT* __restrict__ out, unsigned short* __restrict__ vt,
    int M, int N, int K, int ldo){
  constexpr int LDK = 72;
  __shared__ unsigned short As[128*LDK];
  __shared__ unsigned short Bs[128*LDK];
  const int tid = threadIdx.x;
  const int m0 = blockIdx.x*128, n0 = blockIdx.y*128;
  const int wid = tid>>6, lane = tid&63;
  const int wm = (wid>>1)*64, wn = (wid&1)*64;
  const int lr = lane&15, quad = lane>>4;
  const f32x4 zero4 = {0.f,0.f,0.f,0.f};
  f32x4 acc[4][4];
  #pragma unroll
  for (int i=0;i<4;i++)
    #pragma unroll
    for (int j=0;j<4;j++) acc[i][j] = zero4;
  for (int k0=0; k0<K; k0+=64){
    __syncthreads();
    #pragma unroll
    for (int l=0;l<4;l++){
      int e = tid + l*256;
      int row = e>>3, seg = (e&7)*8;
      int gm = m0+row;
      uint4 va = (gm<M) ? *reinterpret_cast<const uint4*>(&A[(size_t)gm*K + k0 + seg])
                        : make_uint4(0u,0u,0u,0u);
      *reinterpret_cast<uint4*>(&As[row*LDK + seg]) = va;
      int gn = n0+row;
      uint4 vb = (gn<N) ? *reinterpret_cast<const uint4*>(&Bt[(size_t)gn*K + k0 + seg])
                        : make_uint4(0u,0u,0u,0u);
      *reinterpret_cast<uint4*>(&Bs[row*LDK + seg]) = vb;
    }
    __syncthreads();
    #pragma unroll
    for (int kk=0; kk<64; kk+=32){
      bf16x8 af[4], bfr[4];
      #pragma unroll
      for (int i=0;i<4;i++) af[i]  = *reinterpret_cast<const bf16x8*>(&As[(wm+i*16+lr)*LDK + kk + quad*8]);
      #pragma unroll
      for (int j=0;j<4;j++) bfr[j] = *reinterpret_cast<const bf16x8*>(&Bs[(wn+j*16+lr)*LDK + kk + quad*8]);
      #pragma unroll
      for (int i=0;i<4;i++)
        #pragma unroll
        for (int j=0;j<4;j++)
          acc[i][j] = __builtin_amdgcn_mfma_f32_16x16x32_bf16(af[i], bfr[j], acc[i][j], 0, 0, 0);
    }
  }
  #pragma unroll
  for (int i=0;i<4;i++){
    #pragma unroll
    for (int j=0;j<4;j++){
      int gn = n0 + wn + j*16 + lr;
      if (gn >= N) continue;
      float bv = BIAS ? bias[gn] : 0.f;
      #pragma unroll
      for (int r=0;r<4;r++){
        int gm = m0 + wm + i*16 + quad*4 + r;
        if (gm >= M) continue;
        float v = acc[i][j][r] + bv;
        if (RES) v += resid[(size_t)gm*ldo + gn];
        if (SV && gn >= 640){
          vt[(size_t)(gn-640)*4096 + gm] = f2b(v);
        } else {
          if constexpr (sizeof(OT)==2) out[(size_t)gm*ldo + gn] = (OT)f2b(v);
          else                         out[(size_t)gm*ldo + gn] = (OT)v;
        }
      }
    }
  }
}

// ---------------- GEGLU elementwise: G = H[:, :1280] * gelu(H[:, 1280:]) ----------------
__global__ void k_geglu(const unsigned short* __restrict__ H, unsigned short* __restrict__ G){
  int e = blockIdx.x*256 + threadIdx.x;   // 8192*160 threads
  int m = e/160, t = e - m*160;
  const unsigned short* hp = H + (size_t)m*2560 + t*8;
  uint4 xv = *reinterpret_cast<const uint4*>(hp);
  uint4 gv = *reinterpret_cast<const uint4*>(hp + 1280);
  const unsigned short* xu = reinterpret_cast<const unsigned short*>(&xv);
  const unsigned short* gu = reinterpret_cast<const unsigned short*>(&gv);
  unsigned short ov[8];
  #pragma unroll
  for (int d=0; d<8; d++){
    float x = b2f(xu[d]);
    float g = b2f(gu[d]);
    float ge = 0.5f*g*(1.0f + erff(g*0.70710678118654752f));
    ov[d] = f2b(x*ge);
  }
  *reinterpret_cast<uint4*>(G + (size_t)m*1280 + t*8) = *reinterpret_cast<const uint4*>(ov);
}

// ---------------- MFMA flash self-attn ----------------
// 64 queries/block, one head. QK rows stride 640; V pre-transposed in Vtg[d_total][4096].
__global__ __launch_bounds__(256) void k_attn1(const unsigned short* __restrict__ QK,
                                               const unsigned short* __restrict__ Vtg,
                                               unsigned short* __restrict__ Oa){
  constexpr int LP = 72;
  __shared__ unsigned short Qs[64*LP];
  __shared__ unsigned short Ks[64*LP];
  __shared__ unsigned short Vt[48*LP];
  __shared__ unsigned short Ps[64*LP];
  const int b = blockIdx.z, hh = blockIdx.y;
  const int q0 = blockIdx.x*64;
  const int tid = threadIdx.x;
  const int wid = tid>>6, lane = tid&63;
  const int lr = lane&15, quad = lane>>4;
  const int wm = wid*16;
  const float scale = 0.15811388300841898f; // 1/sqrt(40)
  const unsigned short* Qb = QK + ((size_t)b*kNM + q0)*640 + hh*kDH;
  const unsigned short* Kb = QK + ((size_t)b*kNM)*640 + 320 + hh*kDH;
  const unsigned short* Vb = Vtg + (size_t)hh*kDH*4096 + (size_t)b*kNM;
  const uint4 z4 = make_uint4(0u,0u,0u,0u);
  // zero K-dim pads (cols 40..63 of Qs/Ks; rows 40..47 of Vt) once
  for (int e=tid; e<192; e+=256){
    int row=e/3, seg=40+(e%3)*8;
    *reinterpret_cast<uint4*>(&Qs[row*LP+seg]) = z4;
    *reinterpret_cast<uint4*>(&Ks[row*LP+seg]) = z4;
  }
  for (int e=tid; e<72; e+=256){
    int row=40+e/9, seg=(e%9)*8;
    *reinterpret_cast<uint4*>(&Vt[row*LP+seg]) = z4;
  }
  // stage Q once (row-major = A operand layout)
  for (int e=tid; e<320; e+=256){
    int row=e/5, seg=(e%5)*8;
    *reinterpret_cast<uint4*>(&Qs[row*LP+seg]) =
      *reinterpret_cast<const uint4*>(Qb + (size_t)row*640 + seg);
  }
  const f32x4 zf = {0.f,0.f,0.f,0.f};
  f32x4 oacc[3] = {zf, zf, zf};
  float m_i[4], l_i[4];
  #pragma unroll
  for (int r=0;r<4;r++){ m_i[r] = -1e30f; l_i[r] = 0.f; }
  for (int kt=0; kt<kNM; kt+=64){
    __syncthreads();   // prev tile's Ks/Vt reads done
    for (int e=tid; e<320; e+=256){
      int row=e/5, seg=(e%5)*8;
      *reinterpret_cast<uint4*>(&Ks[row*LP+seg]) =
        *reinterpret_cast<const uint4*>(Kb + (size_t)(kt+row)*640 + seg);
    }
    for (int e=tid; e<320; e+=256){
      int d=e>>3, seg=(e&7)*8;
      *reinterpret_cast<uint4*>(&Vt[d*LP+seg]) =
        *reinterpret_cast<const uint4*>(Vb + (size_t)d*4096 + kt + seg);
    }
    __syncthreads();
    // S = Q.K^T  (K-dim = 64 padded head dims, 2 mfma steps)
    f32x4 sacc[4] = {zf, zf, zf, zf};
    bf16x8 aq0 = *reinterpret_cast<const bf16x8*>(&Qs[(wm+lr)*LP + quad*8]);
    bf16x8 aq1 = *reinterpret_cast<const bf16x8*>(&Qs[(wm+lr)*LP + 32 + quad*8]);
    #pragma unroll
    for (int j=0;j<4;j++){
      bf16x8 bk0 = *reinterpret_cast<const bf16x8*>(&Ks[(j*16+lr)*LP + quad*8]);
      sacc[j] = __builtin_amdgcn_mfma_f32_16x16x32_bf16(aq0, bk0, sacc[j], 0,0,0);
      bf16x8 bk1 = *reinterpret_cast<const bf16x8*>(&Ks[(j*16+lr)*LP + 32 + quad*8]);
      sacc[j] = __builtin_amdgcn_mfma_f32_16x16x32_bf16(aq1, bk1, sacc[j], 0,0,0);
    }
    // online softmax per row (m = wm + quad*4 + r); P -> LDS bf16 (A-operand layout)
    #pragma unroll
    for (int r=0;r<4;r++){
      float v0=sacc[0][r]*scale, v1=sacc[1][r]*scale, v2=sacc[2][r]*scale, v3=sacc[3][r]*scale;
      float rm = fmaxf(fmaxf(v0,v1), fmaxf(v2,v3));
      #pragma unroll
      for (int off=1; off<16; off<<=1) rm = fmaxf(rm, __shfl_xor(rm, off, 64));
      float mnew = fmaxf(m_i[r], rm);
      float alpha = __expf(m_i[r] - mnew);
      float p0=__expf(v0-mnew), p1=__expf(v1-mnew), p2=__expf(v2-mnew), p3=__expf(v3-mnew);
      float psum = p0+p1+p2+p3;
      #pragma unroll
      for (int off=1; off<16; off<<=1) psum += __shfl_xor(psum, off, 64);
      l_i[r] = l_i[r]*alpha + psum;
      m_i[r] = mnew;
      int row = wm + quad*4 + r;
      Ps[row*LP +      lr] = f2b(p0);
      Ps[row*LP + 16 + lr] = f2b(p1);
      Ps[row*LP + 32 + lr] = f2b(p2);
      Ps[row*LP + 48 + lr] = f2b(p3);
      oacc[0][r] *= alpha; oacc[1][r] *= alpha; oacc[2][r] *= alpha;
    }
    // O += P.V  (Ps rows written & read by this wave only -> no barrier)
    #pragma unroll
    for (int s=0;s<2;s++){
      bf16x8 ap = *reinterpret_cast<const bf16x8*>(&Ps[(wm+lr)*LP + s*32 + quad*8]);
      #pragma unroll
      for (int nt=0;nt<3;nt++){
        bf16x8 bv = *reinterpret_cast<const bf16x8*>(&Vt[(nt*16+lr)*LP + s*32 + quad*8]);
        oacc[nt] = __builtin_amdgcn_mfma_f32_16x16x32_bf16(ap, bv, oacc[nt], 0,0,0);
      }
    }
  }
  // epilogue: O[m][d], m = wm+quad*4+r, d = nt*16+lr (d<40)
  #pragma unroll
  for (int r=0;r<4;r++){
    float inv = 1.0f / l_i[r];
    unsigned short* Ob = Oa + ((size_t)b*kNM + q0 + wm + quad*4 + r)*kC + hh*kDH;
    #pragma unroll
    for (int nt=0;nt<3;nt++){
      int d = nt*16 + lr;
      if (d < kDH) Ob[d] = f2b(oacc[nt][r]*inv);
    }
  }
}

// ---------------- V2 transpose for MFMA cross-attn: Vt2[b][d=320][tok pad 80] ----------------
__global__ void k_vt2(const unsigned short* __restrict__ KV, unsigned short* __restrict__ Vt2){
  int id = blockIdx.x*256 + threadIdx.x;
  if (id >= kB*320*80) return;
  int tok = id % 80;
  int d   = (id / 80) % 320;
  int b   = id / (80*320);
  unsigned short v = (tok < kLC) ? KV[((size_t)b*kLC + tok)*640 + 320 + d] : (unsigned short)0;
  Vt2[((size_t)b*320 + d)*80 + tok] = v;
}

// ---------------- MFMA one-shot cross-attn: 64 q/block, 77 keys pad 80 ----------------
__global__ __launch_bounds__(256) void k_attn2m(const unsigned short* __restrict__ Q,
                                                const unsigned short* __restrict__ KV,
                                                const unsigned short* __restrict__ Vt2,
                                                unsigned short* __restrict__ Oa){
  constexpr int LP = 72, LP2 = 104;
  __shared__ unsigned short Qs[64*LP];    // [q][d pad64]
  __shared__ unsigned short Ks[80*LP];    // [key pad80][d pad64]
  __shared__ unsigned short Vts[48*LP2];  // [d pad48][key pad96]
  __shared__ unsigned short Ps[64*LP2];   // [q][key pad96]
  const int b = blockIdx.z, hh = blockIdx.y;
  const int q0 = blockIdx.x*64;
  const int tid = threadIdx.x;
  const int wid = tid>>6, lane = tid&63;
  const int lr = lane&15, quad = lane>>4;
  const int wm = wid*16;
  const float scale = 0.15811388300841898f;
  const uint4 z4 = make_uint4(0u,0u,0u,0u);
  // zero everything (pads included): counts are total_shorts/8 per buffer
  for (int e=tid; e<576; e+=256) *reinterpret_cast<uint4*>(&Qs[e*8]) = z4;   // 64*72/8
  for (int e=tid; e<720; e+=256) *reinterpret_cast<uint4*>(&Ks[e*8]) = z4;   // 80*72/8
  for (int e=tid; e<624; e+=256) *reinterpret_cast<uint4*>(&Vts[e*8]) = z4;  // 48*104/8
  for (int e=tid; e<832; e+=256) *reinterpret_cast<uint4*>(&Ps[e*8]) = z4;   // 64*104/8
  __syncthreads();
  // stage
  for (int e=tid; e<320; e+=256){               // Q: 64 rows x 5 seg
    int row=e/5, seg=(e%5)*8;
    *reinterpret_cast<uint4*>(&Qs[row*LP+seg]) =
      *reinterpret_cast<const uint4*>(Q + ((size_t)b*kN + q0 + row)*kC + hh*kDH + seg);
  }
  for (int e=tid; e<385; e+=256){               // K: 77 rows x 5 seg
    int row=e/5, seg=(e%5)*8;
    *reinterpret_cast<uint4*>(&Ks[row*LP+seg]) =
      *reinterpret_cast<const uint4*>(KV + ((size_t)b*kLC + row)*640 + hh*kDH + seg);
  }
  for (int e=tid; e<400; e+=256){               // Vt: 40 rows(d) x 10 seg(80 tok)
    int d=e/10, seg=(e%10)*8;
    *reinterpret_cast<uint4*>(&Vts[d*LP2+seg]) =
      *reinterpret_cast<const uint4*>(Vt2 + ((size_t)b*320 + hh*kDH + d)*80 + seg);
  }
  __syncthreads();
  const f32x4 zf = {0.f,0.f,0.f,0.f};
  // S = Q.K^T : 5 key-frags x 2 ksteps
  f32x4 sacc[5] = {zf, zf, zf, zf, zf};
  bf16x8 aq0 = *reinterpret_cast<const bf16x8*>(&Qs[(wm+lr)*LP + quad*8]);
  bf16x8 aq1 = *reinterpret_cast<const bf16x8*>(&Qs[(wm+lr)*LP + 32 + quad*8]);
  #pragma unroll
  for (int j=0;j<5;j++){
    bf16x8 bk0 = *reinterpret_cast<const bf16x8*>(&Ks[(j*16+lr)*LP + quad*8]);
    sacc[j] = __builtin_amdgcn_mfma_f32_16x16x32_bf16(aq0, bk0, sacc[j], 0,0,0);
    bf16x8 bk1 = *reinterpret_cast<const bf16x8*>(&Ks[(j*16+lr)*LP + 32 + quad*8]);
    sacc[j] = __builtin_amdgcn_mfma_f32_16x16x32_bf16(aq1, bk1, sacc[j], 0,0,0);
  }
  // one-shot softmax per row
  float l_i[4];
  #pragma unroll
  for (int r=0;r<4;r++){
    float vv[5];
    float rm = -1e30f;
    #pragma unroll
    for (int j=0;j<5;j++){
      int c = j*16 + lr;
      vv[j] = sacc[j][r]*scale;
      if (c < kLC) rm = fmaxf(rm, vv[j]);
    }
    #pragma unroll
    for (int off=1; off<16; off<<=1) rm = fmaxf(rm, __shfl_xor(rm, off, 64));
    float psum = 0.f;
    int row = wm + quad*4 + r;
    #pragma unroll
    for (int j=0;j<5;j++){
      int c = j*16 + lr;
      float p = (c < kLC) ? __expf(vv[j]-rm) : 0.f;
      psum += p;
      Ps[row*LP2 + c] = f2b(p);
    }
    #pragma unroll
    for (int off=1; off<16; off<<=1) psum += __shfl_xor(psum, off, 64);
    l_i[r] = psum;
  }
  // O = P.V^T : 3 d-frags x 3 ksteps (keys pad 96)
  f32x4 oacc[3] = {zf, zf, zf};
  #pragma unroll
  for (int s=0;s<3;s++){
    bf16x8 ap = *reinterpret_cast<const bf16x8*>(&Ps[(wm+lr)*LP2 + s*32 + quad*8]);
    #pragma unroll
    for (int nt=0;nt<3;nt++){
      bf16x8 bv = *reinterpret_cast<const bf16x8*>(&Vts[(nt*16+lr)*LP2 + s*32 + quad*8]);
      oacc[nt] = __builtin_amdgcn_mfma_f32_16x16x32_bf16(ap, bv, oacc[nt], 0,0,0);
    }
  }
  #pragma unroll
  for (int r=0;r<4;r++){
    float inv = 1.0f / l_i[r];
    unsigned short* Ob = Oa + ((size_t)b*kN + q0 + wm + quad*4 + r)*kC + hh*kDH;
    #pragma unroll
    for (int nt=0;nt<3;nt++){
      int d = nt*16 + lr;
      if (d < kDH) Ob[d] = f2b(oacc[nt][r]*inv);
    }
  }
}

// ---------------- unmerge + residual ----------------
__global__ void k_unmerge(const float* __restrict__ net, const float* __restrict__ Xo,
                          const int* __restrict__ merged, const int* __restrict__ node_idx,
                          const int* __restrict__ slot_of, float* __restrict__ net1){
  int blk = blockIdx.x; int b = blk >> 12; int t = blk & 4095;
  int h = t>>6, w = t&63;
  int row;
  if (!((h|w)&1)) row = kNB + ((h>>1)*32 + (w>>1));
  else {
    int i = d_arank(h,w);
    row = merged[(size_t)b*kNA+i] ? (kNB + node_idx[(size_t)b*kNA+i]) : slot_of[(size_t)b*kNA+i];
  }
  const float* np_ = net + ((size_t)b*kN + t)*kC;
  const float* xp = Xo + ((size_t)b*kNM + row)*kC;
  float* op = net1 + ((size_t)b*kN + t)*kC;
  int lane = threadIdx.x;
  #pragma unroll
  for (int q=0;q<5;q++){ int c = lane+q*64; op[c] = np_[c] + xp[c]; }
}

// ---------------- launch ----------------
extern "C" void kernel_launch(void* const* d_in, const int* in_sizes, int n_in,
                              void* d_out, int out_size, void* d_ws, size_t ws_size,
                              hipStream_t stream){
  const float* net = (const float*)d_in[0];
  const float* ctx = (const float*)d_in[1];
  const float* ln1g=(const float*)d_in[2], *ln1b=(const float*)d_in[3];
  const float* ln2g=(const float*)d_in[4], *ln2b=(const float*)d_in[5];
  const float* ln3g=(const float*)d_in[6], *ln3b=(const float*)d_in[7];
  const float* w1q=(const float*)d_in[8],  *w1k=(const float*)d_in[9];
  const float* w1v=(const float*)d_in[10], *w1o=(const float*)d_in[11];
  const float* b1o=(const float*)d_in[12];
  const float* w2q=(const float*)d_in[13], *w2k=(const float*)d_in[14];
  const float* w2v=(const float*)d_in[15], *w2o=(const float*)d_in[16];
  const float* b2o=(const float*)d_in[17];
  const float* fw1=(const float*)d_in[18], *fb1=(const float*)d_in[19];
  const float* fw2=(const float*)d_in[20], *fb2=(const float*)d_in[21];

  char* ws = (char*)d_ws;
  float* mnA  = (float*)(ws + B_mnA);
  float* mnB  = (float*)(ws + B_mnB);
  float* y32  = (float*)(ws + B_y32);
  float* xm32 = (float*)(ws + B_xm);
  float* Xo1  = (float*)(ws + B_xo1);
  float* net1 = (float*)(ws + B_net1);
  float* net2 = (float*)(ws + B_net2);
  float* cnt  = (float*)(ws + B_cnt);
  unsigned short* Hb   = (unsigned short*)(ws + B_H);
  unsigned short* Gb   = (unsigned short*)(ws + B_G);
  unsigned short* QKb  = (unsigned short*)(ws + B_QKb);
  unsigned short* Vtg  = (unsigned short*)(ws + B_Vtg);
  unsigned short* yb   = (unsigned short*)(ws + B_yb);
  unsigned short* xmb  = (unsigned short*)(ws + B_xmb);
  unsigned short* Ao1b = (unsigned short*)(ws + B_Ao1b);
  unsigned short* Q2b  = (unsigned short*)(ws + B_Q2b);
  unsigned short* Ao2b = (unsigned short*)(ws + B_Ao2b);
  unsigned short* KV2b = (unsigned short*)(ws + B_KV2b);
  unsigned short* Vt2g = (unsigned short*)(ws + B_Vt2g);
  unsigned short* ctxb = (unsigned short*)(ws + B_ctxb);
  unsigned short* Wqkv = (unsigned short*)(ws + B_Wqkv);
  unsigned short* Wo1  = (unsigned short*)(ws + B_Wo1);
  unsigned short* Wq2  = (unsigned short*)(ws + B_Wq2);
  unsigned short* Wkv2 = (unsigned short*)(ws + B_Wkv2);
  unsigned short* Wo2  = (unsigned short*)(ws + B_Wo2);
  unsigned short* Wff1 = (unsigned short*)(ws + B_Wff1);
  unsigned short* Wff2 = (unsigned short*)(ws + B_Wff2);
  unsigned long long* pack = (unsigned long long*)(ws + B_pack);
  unsigned int* nmkey = (unsigned int*)(ws + B_key);
  int* nidx = (int*)(ws + B_nidx); int* mrg = (int*)(ws + B_mrg); int* slot = (int*)(ws + B_slot);
  int* unml = (int*)(ws + B_unml); int* ucnt = (int*)(ws + B_ucnt); int* aidx = (int*)(ws + B_aidx);

  // --- batched weight conversion + ctx convert (570 transpose tiles + 58 copy blocks) ---
  k_wt_all<<<628, 256, 0, stream>>>(w1q, w1k, w1v, w1o, w2q, w2k, w2v, w2o, fw1, fw2,
                                    Wqkv, Wo1, Wq2, Wkv2, Wo2, Wff1, Wff2, ctx, ctxb);

  // --- ToMe indices (exact fp32) ---
  k_idx   <<<16, 256, 0, stream>>>(aidx);
  k_init  <<<(kB*kNA+255)/256, 256, 0, stream>>>(pack, ucnt);
  k_gather<<<kB*kN, 64, 0, stream>>>(net, mnA, mnB);
  k_scores<<<dim3(kNA/64, kNB/64, kB), 256, 0, stream>>>(mnA, mnB, pack);
  k_decode<<<(kB*kNA+255)/256, 256, 0, stream>>>(pack, nmkey, nidx);
  k_rank  <<<dim3(kNA/256, kB), 256, 0, stream>>>(nmkey, mrg, slot, unml, ucnt);
  // --- merge(LN1(net)) ---
  k_ln<false><<<kB*kN, 64, 0, stream>>>(net, ln1g, ln1b, y32);
  k_merge_unm  <<<kB*kNB, 64, 0, stream>>>(y32, aidx, unml, xmb);
  k_merge_dst  <<<kB*kNB, 64, 0, stream>>>(y32, xm32, cnt);
  k_merge_src  <<<kB*kNA, 64, 0, stream>>>(y32, aidx, mrg, nidx, xm32, cnt);
  k_merge_scale<<<kB*kNB, 64, 0, stream>>>(xm32, cnt, xmb);
  // --- attn1 (self, merged seq): QKV gemm writes Q|K rows + V transposed ---
  k_bgemm<unsigned short,false,false,true><<<dim3(32,8), 256, 0, stream>>>(
      xmb, Wqkv, nullptr, nullptr, QKb, Vtg, 4096, 960, 320, 640);
  k_attn1<<<dim3(kNM/64, kH, kB), 256, 0, stream>>>(QKb, Vtg, Ao1b);
  k_bgemm<float,true,false,false><<<dim3(32,3), 256, 0, stream>>>(
      Ao1b, Wo1, b1o, nullptr, Xo1, nullptr, 4096, 320, 320, 320);
  k_unmerge<<<kB*kN, 64, 0, stream>>>(net, Xo1, mrg, nidx, slot, net1);
  // --- attn2 (cross) ---
  k_ln<true><<<kB*kN, 64, 0, stream>>>(net1, ln2g, ln2b, yb);
  k_bgemm<unsigned short,false,false,false><<<dim3(64,3), 256, 0, stream>>>(
      yb, Wq2, nullptr, nullptr, Q2b, nullptr, 8192, 320, 320, 320);
  k_bgemm<unsigned short,false,false,false><<<dim3(2,5), 256, 0, stream>>>(
      ctxb, Wkv2, nullptr, nullptr, KV2b, nullptr, 154, 640, 768, 640);
  k_vt2<<<(kB*320*80+255)/256, 256, 0, stream>>>(KV2b, Vt2g);
  k_attn2m<<<dim3(kN/64, kH, kB), 256, 0, stream>>>(Q2b, KV2b, Vt2g, Ao2b);
  k_bgemm<float,true,true,false><<<dim3(64,3), 256, 0, stream>>>(
      Ao2b, Wo2, b2o, net1, net2, nullptr, 8192, 320, 320, 320);
  // --- GEGLU FF ---
  k_ln<true><<<kB*kN, 64, 0, stream>>>(net2, ln3g, ln3b, yb);
  k_bgemm<unsigned short,true,false,false><<<dim3(64,20), 256, 0, stream>>>(
      yb, Wff1, fb1, nullptr, Hb, nullptr, 8192, 2560, 320, 2560);
  k_geglu<<<(kB*kN*160+255)/256, 256, 0, stream>>>(Hb, Gb);
  k_bgemm<float,true,true,false><<<dim3(64,3), 256, 0, stream>>>(
      Gb, Wff2, fb2, net2, (float*)d_out, nullptr, 8192, 320, 1280, 320);
}